// Round 1
// baseline (1725.507 us; speedup 1.0000x reference)
//
#include <hip/hip_runtime.h>
#include <cstdint>

// B=4, T=4096, D=1024, H=16, d=64, C=64, N=T/C=64
#define B_ 4
#define T_ 4096
#define D_ 1024
#define H_ 16
#define HD_ 64
#define N_ 64

// ---------------------------------------------------------------------------
// K1: qkv = x @ Wqkv^T  (M=16384, N=3072, K=1024), fp32 vector GEMM.
// Epilogue splits j -> (s,h,dd): s=0 -> Q (scaled 1/8, [B,H,T,d] f32),
// s=1/2 -> K8/V8 (sign, int8 +-1, [B,H,T,d]).
// 128x128 tile, BK=16, 256 threads, 8x8 micro-tile.
// ---------------------------------------------------------------------------
__global__ __launch_bounds__(256)
void k_qkv(const float* __restrict__ X, const float* __restrict__ W,
           float* __restrict__ Q, signed char* __restrict__ K8,
           signed char* __restrict__ V8)
{
    __shared__ float As[16][128];
    __shared__ float Bs[16][128];
    const int tid = threadIdx.x;
    const int tr = tid >> 4, tc = tid & 15;
    const int row0 = blockIdx.y * 128;   // bt tile
    const int col0 = blockIdx.x * 128;   // j tile
    const int lr = tid >> 1;             // 0..127
    const int lco = (tid & 1) * 8;       // 0 or 8

    const float* xrow = X + (size_t)(row0 + lr) * D_ + lco;
    const float* wrow = W + (size_t)(col0 + lr) * D_ + lco;

    float acc[8][8];
    #pragma unroll
    for (int i = 0; i < 8; ++i)
        #pragma unroll
        for (int j = 0; j < 8; ++j) acc[i][j] = 0.f;

    for (int k0 = 0; k0 < D_; k0 += 16) {
        float4 a0 = *(const float4*)(xrow + k0);
        float4 a1 = *(const float4*)(xrow + k0 + 4);
        float4 b0 = *(const float4*)(wrow + k0);
        float4 b1 = *(const float4*)(wrow + k0 + 4);
        __syncthreads();
        As[lco+0][lr]=a0.x; As[lco+1][lr]=a0.y; As[lco+2][lr]=a0.z; As[lco+3][lr]=a0.w;
        As[lco+4][lr]=a1.x; As[lco+5][lr]=a1.y; As[lco+6][lr]=a1.z; As[lco+7][lr]=a1.w;
        Bs[lco+0][lr]=b0.x; Bs[lco+1][lr]=b0.y; Bs[lco+2][lr]=b0.z; Bs[lco+3][lr]=b0.w;
        Bs[lco+4][lr]=b1.x; Bs[lco+5][lr]=b1.y; Bs[lco+6][lr]=b1.z; Bs[lco+7][lr]=b1.w;
        __syncthreads();
        #pragma unroll
        for (int kk = 0; kk < 16; ++kk) {
            float a[8], b[8];
            *(float4*)&a[0] = *(const float4*)&As[kk][tr*8];
            *(float4*)&a[4] = *(const float4*)&As[kk][tr*8+4];
            *(float4*)&b[0] = *(const float4*)&Bs[kk][tc*8];
            *(float4*)&b[4] = *(const float4*)&Bs[kk][tc*8+4];
            #pragma unroll
            for (int i = 0; i < 8; ++i)
                #pragma unroll
                for (int j = 0; j < 8; ++j)
                    acc[i][j] = fmaf(a[i], b[j], acc[i][j]);
        }
    }

    const int jbase = col0 + tc * 8;       // column of first acc col
    const int s  = jbase >> 10;            // 0:q 1:k 2:v (uniform per block)
    const int h  = (jbase & 1023) >> 6;
    const int dd = jbase & 63;             // multiple of 8
    #pragma unroll
    for (int i = 0; i < 8; ++i) {
        const int bt = row0 + tr * 8 + i;
        const int bb = bt >> 12;           // /T_
        const int t  = bt & (T_ - 1);
        const size_t base = (((size_t)(bb * H_ + h)) * T_ + t) * HD_ + dd;
        if (s == 0) {
            float4 o0, o1;
            o0.x = acc[i][0]*0.125f; o0.y = acc[i][1]*0.125f;
            o0.z = acc[i][2]*0.125f; o0.w = acc[i][3]*0.125f;
            o1.x = acc[i][4]*0.125f; o1.y = acc[i][5]*0.125f;
            o1.z = acc[i][6]*0.125f; o1.w = acc[i][7]*0.125f;
            *(float4*)(Q + base)     = o0;
            *(float4*)(Q + base + 4) = o1;
        } else {
            union { signed char c[8]; long long ll; } u;
            #pragma unroll
            for (int j = 0; j < 8; ++j) u.c[j] = (acc[i][j] >= 0.f) ? 1 : -1;
            signed char* dst = (s == 1 ? K8 : V8) + base;
            *(long long*)dst = u.ll;
        }
    }
}

// ---------------------------------------------------------------------------
// K2: per chunk (b,h,n): intra = tril(q k^T) v  -> OM[b,t,h*64+dd]
//     and chunk_kv[kdim][dd] = sum_c k[c][kdim] v[c][dd] -> CKV.
// LDS: qsT/ksT = [feature][time] (transposed), vsn = [time][feature],
//      ssT = [j][i]. 4x4 register tiles, float4 LDS reads.
// ---------------------------------------------------------------------------
__global__ __launch_bounds__(256)
void k_chunk(const float* __restrict__ Q, const signed char* __restrict__ K8,
             const signed char* __restrict__ V8, float* __restrict__ OM,
             float* __restrict__ CKV)
{
    __shared__ float qsT[64][64];
    __shared__ float ksT[64][64];
    __shared__ float vsn[64][64];
    __shared__ float ssT[64][64];
    const int tid = threadIdx.x;
    const int bh = blockIdx.x >> 6;
    const int n  = blockIdx.x & 63;
    const int tr = tid >> 4, tc = tid & 15;
    const int i0 = tr * 4, c0 = tc * 4;

    // load q (transpose into qsT[feature][time])
    const float* qg = Q + ((size_t)bh * T_ + n * 64) * 64;
    #pragma unroll
    for (int p = 0; p < 4; ++p) {
        const int off = p * 1024 + tid * 4;
        float4 v = *(const float4*)(qg + off);
        const int row = off >> 6, col = off & 63;
        qsT[col+0][row] = v.x; qsT[col+1][row] = v.y;
        qsT[col+2][row] = v.z; qsT[col+3][row] = v.w;
    }
    {
        const signed char* kg = K8 + ((size_t)bh * T_ + n * 64) * 64;
        int4 kw = *(const int4*)(kg + tid * 16);
        const signed char* kc = (const signed char*)&kw;
        const int row = tid >> 2, colb = (tid & 3) * 16;
        #pragma unroll
        for (int c = 0; c < 16; ++c) ksT[colb + c][row] = (float)kc[c];

        const signed char* vg = V8 + ((size_t)bh * T_ + n * 64) * 64;
        int4 vw = *(const int4*)(vg + tid * 16);
        const signed char* vcp = (const signed char*)&vw;
        #pragma unroll
        for (int q4 = 0; q4 < 4; ++q4) {
            float4 t4;
            t4.x = (float)vcp[q4*4+0]; t4.y = (float)vcp[q4*4+1];
            t4.z = (float)vcp[q4*4+2]; t4.w = (float)vcp[q4*4+3];
            *(float4*)&vsn[row][colb + q4*4] = t4;
        }
    }
    __syncthreads();

    // Phase A: scores s[i][j] = q_i . k_j (masked j<=i) -> ssT[j][i]
    float pa[4][4];
    #pragma unroll
    for (int r = 0; r < 4; ++r)
        #pragma unroll
        for (int c = 0; c < 4; ++c) pa[r][c] = 0.f;
    for (int dd = 0; dd < 64; ++dd) {
        float4 qv = *(const float4*)&qsT[dd][i0];
        float4 kv = *(const float4*)&ksT[dd][c0];
        const float ar[4] = {qv.x, qv.y, qv.z, qv.w};
        const float bc[4] = {kv.x, kv.y, kv.z, kv.w};
        #pragma unroll
        for (int r = 0; r < 4; ++r)
            #pragma unroll
            for (int c = 0; c < 4; ++c)
                pa[r][c] = fmaf(ar[r], bc[c], pa[r][c]);
    }
    #pragma unroll
    for (int r = 0; r < 4; ++r)
        #pragma unroll
        for (int c = 0; c < 4; ++c) {
            const int i = i0 + r, j = c0 + c;
            ssT[j][i] = (j <= i) ? pa[r][c] : 0.f;
        }
    __syncthreads();

    // Phase B: intra[i][dd] = sum_j s[i][j] v[j][dd]
    float pb[4][4];
    #pragma unroll
    for (int r = 0; r < 4; ++r)
        #pragma unroll
        for (int c = 0; c < 4; ++c) pb[r][c] = 0.f;
    for (int j = 0; j < 64; ++j) {
        float4 sv = *(const float4*)&ssT[j][i0];
        float4 vv = *(const float4*)&vsn[j][c0];
        const float ar[4] = {sv.x, sv.y, sv.z, sv.w};
        const float bc[4] = {vv.x, vv.y, vv.z, vv.w};
        #pragma unroll
        for (int r = 0; r < 4; ++r)
            #pragma unroll
            for (int c = 0; c < 4; ++c)
                pb[r][c] = fmaf(ar[r], bc[c], pb[r][c]);
    }
    const int bb = bh >> 4, h = bh & 15;
    #pragma unroll
    for (int r = 0; r < 4; ++r) {
        const int t = n * 64 + i0 + r;
        float4 o; o.x = pb[r][0]; o.y = pb[r][1]; o.z = pb[r][2]; o.w = pb[r][3];
        *(float4*)&OM[((size_t)bb * T_ + t) * D_ + h * 64 + c0] = o;
    }

    // Phase C: ckv[kdim][dd] = sum_c k[c][kdim] v[c][dd]
    float pc4[4][4];
    #pragma unroll
    for (int r = 0; r < 4; ++r)
        #pragma unroll
        for (int c = 0; c < 4; ++c) pc4[r][c] = 0.f;
    for (int c = 0; c < 64; ++c) {
        float kr[4];
        #pragma unroll
        for (int r = 0; r < 4; ++r) kr[r] = ksT[i0 + r][c];
        float4 vv = *(const float4*)&vsn[c][c0];
        const float bc[4] = {vv.x, vv.y, vv.z, vv.w};
        #pragma unroll
        for (int r = 0; r < 4; ++r)
            #pragma unroll
            for (int cc = 0; cc < 4; ++cc)
                pc4[r][cc] = fmaf(kr[r], bc[cc], pc4[r][cc]);
    }
    #pragma unroll
    for (int r = 0; r < 4; ++r) {
        float4 o; o.x = pc4[r][0]; o.y = pc4[r][1]; o.z = pc4[r][2]; o.w = pc4[r][3];
        *(float4*)&CKV[(((size_t)bh) * N_ + n) * 4096 + (i0 + r) * 64 + c0] = o;
    }
}

// ---------------------------------------------------------------------------
// K3: in-place exclusive scan of CKV over chunks, per (b,h) entry; also
// writes final_matrix (= inclusive total) and final_count.
// ---------------------------------------------------------------------------
__global__ __launch_bounds__(256)
void k_scan(float* __restrict__ CKV, float* __restrict__ FM, float* __restrict__ FC)
{
    const int bh = blockIdx.x >> 4;
    const int e  = (blockIdx.x & 15) * 256 + threadIdx.x;  // 0..4095
    const size_t base = (size_t)bh * N_ * 4096 + e;
    float vals[64];
    #pragma unroll
    for (int nn = 0; nn < 64; ++nn) vals[nn] = CKV[base + (size_t)nn * 4096];
    float run = 0.f;
    #pragma unroll
    for (int nn = 0; nn < 64; ++nn) {
        CKV[base + (size_t)nn * 4096] = run;
        run += vals[nn];
    }
    FM[(size_t)bh * 4096 + e] = run;
    if ((blockIdx.x & 15) == 0 && threadIdx.x == 0) FC[bh] = (float)T_;
}

// ---------------------------------------------------------------------------
// K4: cross[i][dd] = sum_k q[i][k] prefix[k][dd]; OM = (intra+cross)/total.
// ---------------------------------------------------------------------------
__global__ __launch_bounds__(256)
void k_cross(const float* __restrict__ Q, const float* __restrict__ CKV,
             float* __restrict__ OM)
{
    __shared__ float qsT[64][64];
    __shared__ float ps[64][64];
    const int tid = threadIdx.x;
    const int bh = blockIdx.x >> 6, n = blockIdx.x & 63;
    const int tr = tid >> 4, tc = tid & 15;
    const int i0 = tr * 4, c0 = tc * 4;

    const float* qg = Q + ((size_t)bh * T_ + n * 64) * 64;
    #pragma unroll
    for (int p = 0; p < 4; ++p) {
        const int off = p * 1024 + tid * 4;
        float4 v = *(const float4*)(qg + off);
        const int row = off >> 6, col = off & 63;
        qsT[col+0][row] = v.x; qsT[col+1][row] = v.y;
        qsT[col+2][row] = v.z; qsT[col+3][row] = v.w;
    }
    const float* pg = CKV + ((size_t)bh * N_ + n) * 4096;
    #pragma unroll
    for (int p = 0; p < 4; ++p) {
        const int off = p * 1024 + tid * 4;
        *(float4*)(&ps[0][0] + off) = *(const float4*)(pg + off);
    }
    __syncthreads();

    float pa[4][4];
    #pragma unroll
    for (int r = 0; r < 4; ++r)
        #pragma unroll
        for (int c = 0; c < 4; ++c) pa[r][c] = 0.f;
    for (int k = 0; k < 64; ++k) {
        float4 qv = *(const float4*)&qsT[k][i0];
        float4 pv = *(const float4*)&ps[k][c0];
        const float ar[4] = {qv.x, qv.y, qv.z, qv.w};
        const float bc[4] = {pv.x, pv.y, pv.z, pv.w};
        #pragma unroll
        for (int r = 0; r < 4; ++r)
            #pragma unroll
            for (int c = 0; c < 4; ++c)
                pa[r][c] = fmaf(ar[r], bc[c], pa[r][c]);
    }
    const int bb = bh >> 4, h = bh & 15;
    #pragma unroll
    for (int r = 0; r < 4; ++r) {
        const int t = n * 64 + i0 + r;
        const float inv = 1.0f / (float)(t + 1);
        const size_t o = ((size_t)bb * T_ + t) * D_ + h * 64 + c0;
        float4 cur = *(float4*)&OM[o];
        cur.x = (cur.x + pa[r][0]) * inv;
        cur.y = (cur.y + pa[r][1]) * inv;
        cur.z = (cur.z + pa[r][2]) * inv;
        cur.w = (cur.w + pa[r][3]) * inv;
        *(float4*)&OM[o] = cur;
    }
}

// ---------------------------------------------------------------------------
// K5: y = OM @ Wo^T  (M=16384, N=1024, K=1024), same structure as K1.
// ---------------------------------------------------------------------------
__global__ __launch_bounds__(256)
void k_out(const float* __restrict__ A, const float* __restrict__ W,
           float* __restrict__ Y)
{
    __shared__ float As[16][128];
    __shared__ float Bs[16][128];
    const int tid = threadIdx.x;
    const int tr = tid >> 4, tc = tid & 15;
    const int row0 = blockIdx.y * 128;
    const int col0 = blockIdx.x * 128;
    const int lr = tid >> 1;
    const int lco = (tid & 1) * 8;

    const float* arow = A + (size_t)(row0 + lr) * D_ + lco;
    const float* wrow = W + (size_t)(col0 + lr) * D_ + lco;

    float acc[8][8];
    #pragma unroll
    for (int i = 0; i < 8; ++i)
        #pragma unroll
        for (int j = 0; j < 8; ++j) acc[i][j] = 0.f;

    for (int k0 = 0; k0 < D_; k0 += 16) {
        float4 a0 = *(const float4*)(arow + k0);
        float4 a1 = *(const float4*)(arow + k0 + 4);
        float4 b0 = *(const float4*)(wrow + k0);
        float4 b1 = *(const float4*)(wrow + k0 + 4);
        __syncthreads();
        As[lco+0][lr]=a0.x; As[lco+1][lr]=a0.y; As[lco+2][lr]=a0.z; As[lco+3][lr]=a0.w;
        As[lco+4][lr]=a1.x; As[lco+5][lr]=a1.y; As[lco+6][lr]=a1.z; As[lco+7][lr]=a1.w;
        Bs[lco+0][lr]=b0.x; Bs[lco+1][lr]=b0.y; Bs[lco+2][lr]=b0.z; Bs[lco+3][lr]=b0.w;
        Bs[lco+4][lr]=b1.x; Bs[lco+5][lr]=b1.y; Bs[lco+6][lr]=b1.z; Bs[lco+7][lr]=b1.w;
        __syncthreads();
        #pragma unroll
        for (int kk = 0; kk < 16; ++kk) {
            float a[8], b[8];
            *(float4*)&a[0] = *(const float4*)&As[kk][tr*8];
            *(float4*)&a[4] = *(const float4*)&As[kk][tr*8+4];
            *(float4*)&b[0] = *(const float4*)&Bs[kk][tc*8];
            *(float4*)&b[4] = *(const float4*)&Bs[kk][tc*8+4];
            #pragma unroll
            for (int i = 0; i < 8; ++i)
                #pragma unroll
                for (int j = 0; j < 8; ++j)
                    acc[i][j] = fmaf(a[i], b[j], acc[i][j]);
        }
    }

    #pragma unroll
    for (int i = 0; i < 8; ++i) {
        const size_t o = (size_t)(row0 + tr*8 + i) * D_ + col0 + tc*8;
        float4 o0, o1;
        o0.x = acc[i][0]; o0.y = acc[i][1]; o0.z = acc[i][2]; o0.w = acc[i][3];
        o1.x = acc[i][4]; o1.y = acc[i][5]; o1.z = acc[i][6]; o1.w = acc[i][7];
        *(float4*)(Y + o)     = o0;
        *(float4*)(Y + o + 4) = o1;
    }
}

extern "C" void kernel_launch(void* const* d_in, const int* in_sizes, int n_in,
                              void* d_out, int out_size, void* d_ws, size_t ws_size,
                              hipStream_t stream)
{
    const float* X    = (const float*)d_in[0];
    const float* Wqkv = (const float*)d_in[1];
    const float* Wo   = (const float*)d_in[2];

    float* Y  = (float*)d_out;                       // [B,T,D]
    float* FM = Y + (size_t)B_ * T_ * D_;            // [B,H,64,64]
    float* FC = FM + (size_t)B_ * H_ * HD_ * HD_;    // [B,H,1,1]

    char* ws = (char*)d_ws;
    float*       Q   = (float*)ws;                       // 64 MiB
    signed char* K8  = (signed char*)(ws + 67108864);    // 16 MiB
    signed char* V8  = (signed char*)(ws + 83886080);    // 16 MiB
    float*       CKV = (float*)(ws + 100663296);         // 64 MiB
    float*       OM  = (float*)(ws + 167772160);         // 64 MiB
    if (ws_size < (size_t)234881024) return;             // need 224 MiB scratch

    dim3 blk(256);
    k_qkv  <<<dim3(24, 128), blk, 0, stream>>>(X, Wqkv, Q, K8, V8);
    k_chunk<<<dim3(4096),    blk, 0, stream>>>(Q, K8, V8, OM, CKV);
    k_scan <<<dim3(1024),    blk, 0, stream>>>(CKV, FM, FC);
    k_cross<<<dim3(4096),    blk, 0, stream>>>(Q, CKV, OM);
    k_out  <<<dim3(8, 128),  blk, 0, stream>>>(OM, Wo, Y);
}

// Round 2
// 731.597 us; speedup vs baseline: 2.3585x; 2.3585x over previous
//
#include <hip/hip_runtime.h>
#include <cstdint>

// B=4, T=4096, D=1024, H=16, d=64, C=64, N=T/C=64
#define B_ 4
#define T_ 4096
#define D_ 1024
#define H_ 16
#define HD_ 64
#define N_ 64

typedef __attribute__((ext_vector_type(8))) short s16x8;
typedef __attribute__((ext_vector_type(4))) float f32x4;

__device__ inline unsigned short f2bf(float f) {
    unsigned int u = __builtin_bit_cast(unsigned int, f);
    u += 0x7fffu + ((u >> 16) & 1u);          // RNE
    return (unsigned short)(u >> 16);
}
__device__ inline float bf2f(unsigned short h) {
    unsigned int u = ((unsigned int)h) << 16;
    return __builtin_bit_cast(float, u);
}
// LDS swizzle: row-major [128][32] bf16 (64B rows); XOR row bits into 16B-slot
// bits so 16-lane column reads spread across all banks. Returns short index.
__device__ inline int swz(int row, int kb) {
    int byte = (row << 6) + (kb << 1);
    byte ^= (row & 7) << 4;
    return byte >> 1;
}

// ---------------------------------------------------------------------------
// Split-bf16 MFMA GEMM: O = A @ Bw^T, M=16384, K=1024, N=128*NCB.
// fp32 inputs converted on-the-fly to (hi,lo) bf16 during LDS staging;
// acc += ah*bh + ah*bl + al*bh  (~2^-16 effective relative error).
// 128x128 tile, BK=32, 256 threads (4 waves, 2x2), 16x16x32 MFMA.
// MODE 0: qkv epilogue (Q fp32 scaled, K8/V8 sign int8). MODE 1: plain store.
// ---------------------------------------------------------------------------
template<int MODE, int NCB>
__global__ __launch_bounds__(256)
void k_gemm(const float* __restrict__ A, const float* __restrict__ Bw,
            float* __restrict__ OQ, signed char* __restrict__ K8,
            signed char* __restrict__ V8, float* __restrict__ Y)
{
    __shared__ short Ah[128 * 32];
    __shared__ short Al[128 * 32];
    __shared__ short Bh[128 * 32];
    __shared__ short Bl[128 * 32];

    const int tid = threadIdx.x;
    const int nwg = 128 * NCB;
    const int bid = blockIdx.x;
    const int sz  = (bid & 7) * (nwg >> 3) + (bid >> 3);   // XCD-contiguous
    const int cb  = sz % NCB, rb = sz / NCB;
    const int row0 = rb * 128, col0 = cb * 128;

    // staging: thread t owns row (t>>1), half (t&1) -> 16 floats of A and B
    const int srow = tid >> 1, shalf = tid & 1;
    const float* ag = A  + (size_t)(row0 + srow) * D_ + shalf * 16;
    const float* bg = Bw + (size_t)(col0 + srow) * D_ + shalf * 16;

    f32x4 acc[4][4];
    #pragma unroll
    for (int i = 0; i < 4; ++i)
        #pragma unroll
        for (int j = 0; j < 4; ++j) acc[i][j] = (f32x4)0.f;

    const int lane = tid & 63, wid = tid >> 6;
    const int wr = wid >> 1, wc = wid & 1;
    const int cl = lane & 15, rg = lane >> 4;
    const int kb8 = rg * 8;

    float4 a[4], b[4];
    #pragma unroll
    for (int i = 0; i < 4; ++i) {
        a[i] = *(const float4*)(ag + i * 4);
        b[i] = *(const float4*)(bg + i * 4);
    }

    for (int k0 = 0; k0 < D_; k0 += 32) {
        __syncthreads();
        // convert + swizzled LDS write (2x s16x8 per tensor per thread)
        const int base = shalf * 16;
        #pragma unroll
        for (int half8 = 0; half8 < 2; ++half8) {
            s16x8 vh, vl, wh, wl;
            #pragma unroll
            for (int j = 0; j < 8; ++j) {
                float fa = ((const float*)a)[half8 * 8 + j];
                unsigned short h = f2bf(fa);
                vh[j] = (short)h;
                vl[j] = (short)f2bf(fa - bf2f(h));
                float fb = ((const float*)b)[half8 * 8 + j];
                unsigned short g = f2bf(fb);
                wh[j] = (short)g;
                wl[j] = (short)f2bf(fb - bf2f(g));
            }
            const int idx = swz(srow, base + half8 * 8);
            *(s16x8*)&Ah[idx] = vh;
            *(s16x8*)&Al[idx] = vl;
            *(s16x8*)&Bh[idx] = wh;
            *(s16x8*)&Bl[idx] = wl;
        }
        __syncthreads();

        // prefetch next tile while MFMA runs
        if (k0 + 32 < D_) {
            #pragma unroll
            for (int i = 0; i < 4; ++i) {
                a[i] = *(const float4*)(ag + k0 + 32 + i * 4);
                b[i] = *(const float4*)(bg + k0 + 32 + i * 4);
            }
        }

        s16x8 fah[4], fal[4];
        #pragma unroll
        for (int mi = 0; mi < 4; ++mi) {
            const int idx = swz(wr * 64 + mi * 16 + cl, kb8);
            fah[mi] = *(const s16x8*)&Ah[idx];
            fal[mi] = *(const s16x8*)&Al[idx];
        }
        #pragma unroll
        for (int ni = 0; ni < 4; ++ni) {
            const int idx = swz(wc * 64 + ni * 16 + cl, kb8);
            s16x8 fbh = *(const s16x8*)&Bh[idx];
            s16x8 fbl = *(const s16x8*)&Bl[idx];
            #pragma unroll
            for (int mi = 0; mi < 4; ++mi) {
                acc[mi][ni] = __builtin_amdgcn_mfma_f32_16x16x32_bf16(fah[mi], fbh, acc[mi][ni], 0, 0, 0);
                acc[mi][ni] = __builtin_amdgcn_mfma_f32_16x16x32_bf16(fah[mi], fbl, acc[mi][ni], 0, 0, 0);
                acc[mi][ni] = __builtin_amdgcn_mfma_f32_16x16x32_bf16(fal[mi], fbh, acc[mi][ni], 0, 0, 0);
            }
        }
    }

    const int m0 = row0 + wr * 64, n0 = col0 + wc * 64;
    if (MODE == 0) {
        const int s = col0 >> 10;               // 0:q 1:k 2:v, uniform/block
        #pragma unroll
        for (int ni = 0; ni < 4; ++ni) {
            const int col = n0 + ni * 16 + cl;
            const int h = (col & 1023) >> 6, dd = col & 63;
            #pragma unroll
            for (int mi = 0; mi < 4; ++mi)
                #pragma unroll
                for (int r = 0; r < 4; ++r) {
                    const int bt = m0 + mi * 16 + rg * 4 + r;
                    const int bb = bt >> 12, t = bt & (T_ - 1);
                    const size_t o = ((size_t)(bb * H_ + h) * T_ + t) * HD_ + dd;
                    const float v = acc[mi][ni][r];
                    if (s == 0)      OQ[o] = v * 0.125f;
                    else if (s == 1) K8[o] = v >= 0.f ? 1 : -1;
                    else             V8[o] = v >= 0.f ? 1 : -1;
                }
        }
    } else {
        #pragma unroll
        for (int ni = 0; ni < 4; ++ni) {
            const int col = n0 + ni * 16 + cl;
            #pragma unroll
            for (int mi = 0; mi < 4; ++mi)
                #pragma unroll
                for (int r = 0; r < 4; ++r)
                    Y[(size_t)(m0 + mi * 16 + rg * 4 + r) * D_ + col] = acc[mi][ni][r];
        }
    }
}

// ---------------------------------------------------------------------------
// K2: per chunk (b,h,n): intra = tril(q k^T) v  -> OM[b,t,h*64+dd]
//     and chunk_kv[kdim][dd] = sum_c k[c][kdim] v[c][dd] -> CKV.
// ---------------------------------------------------------------------------
__global__ __launch_bounds__(256)
void k_chunk(const float* __restrict__ Q, const signed char* __restrict__ K8,
             const signed char* __restrict__ V8, float* __restrict__ OM,
             float* __restrict__ CKV)
{
    __shared__ float qsT[64][64];
    __shared__ float ksT[64][64];
    __shared__ float vsn[64][64];
    __shared__ float ssT[64][64];
    const int tid = threadIdx.x;
    const int bh = blockIdx.x >> 6;
    const int n  = blockIdx.x & 63;
    const int tr = tid >> 4, tc = tid & 15;
    const int i0 = tr * 4, c0 = tc * 4;

    const float* qg = Q + ((size_t)bh * T_ + n * 64) * 64;
    #pragma unroll
    for (int p = 0; p < 4; ++p) {
        const int off = p * 1024 + tid * 4;
        float4 v = *(const float4*)(qg + off);
        const int row = off >> 6, col = off & 63;
        qsT[col+0][row] = v.x; qsT[col+1][row] = v.y;
        qsT[col+2][row] = v.z; qsT[col+3][row] = v.w;
    }
    {
        const signed char* kg = K8 + ((size_t)bh * T_ + n * 64) * 64;
        int4 kw = *(const int4*)(kg + tid * 16);
        const signed char* kc = (const signed char*)&kw;
        const int row = tid >> 2, colb = (tid & 3) * 16;
        #pragma unroll
        for (int c = 0; c < 16; ++c) ksT[colb + c][row] = (float)kc[c];

        const signed char* vg = V8 + ((size_t)bh * T_ + n * 64) * 64;
        int4 vw = *(const int4*)(vg + tid * 16);
        const signed char* vcp = (const signed char*)&vw;
        #pragma unroll
        for (int q4 = 0; q4 < 4; ++q4) {
            float4 t4;
            t4.x = (float)vcp[q4*4+0]; t4.y = (float)vcp[q4*4+1];
            t4.z = (float)vcp[q4*4+2]; t4.w = (float)vcp[q4*4+3];
            *(float4*)&vsn[row][colb + q4*4] = t4;
        }
    }
    __syncthreads();

    float pa[4][4];
    #pragma unroll
    for (int r = 0; r < 4; ++r)
        #pragma unroll
        for (int c = 0; c < 4; ++c) pa[r][c] = 0.f;
    for (int dd = 0; dd < 64; ++dd) {
        float4 qv = *(const float4*)&qsT[dd][i0];
        float4 kv = *(const float4*)&ksT[dd][c0];
        const float ar[4] = {qv.x, qv.y, qv.z, qv.w};
        const float bc[4] = {kv.x, kv.y, kv.z, kv.w};
        #pragma unroll
        for (int r = 0; r < 4; ++r)
            #pragma unroll
            for (int c = 0; c < 4; ++c)
                pa[r][c] = fmaf(ar[r], bc[c], pa[r][c]);
    }
    #pragma unroll
    for (int r = 0; r < 4; ++r)
        #pragma unroll
        for (int c = 0; c < 4; ++c) {
            const int i = i0 + r, j = c0 + c;
            ssT[j][i] = (j <= i) ? pa[r][c] : 0.f;
        }
    __syncthreads();

    float pb[4][4];
    #pragma unroll
    for (int r = 0; r < 4; ++r)
        #pragma unroll
        for (int c = 0; c < 4; ++c) pb[r][c] = 0.f;
    for (int j = 0; j < 64; ++j) {
        float4 sv = *(const float4*)&ssT[j][i0];
        float4 vv = *(const float4*)&vsn[j][c0];
        const float ar[4] = {sv.x, sv.y, sv.z, sv.w};
        const float bc[4] = {vv.x, vv.y, vv.z, vv.w};
        #pragma unroll
        for (int r = 0; r < 4; ++r)
            #pragma unroll
            for (int c = 0; c < 4; ++c)
                pb[r][c] = fmaf(ar[r], bc[c], pb[r][c]);
    }
    const int bb = bh >> 4, h = bh & 15;
    #pragma unroll
    for (int r = 0; r < 4; ++r) {
        const int t = n * 64 + i0 + r;
        float4 o; o.x = pb[r][0]; o.y = pb[r][1]; o.z = pb[r][2]; o.w = pb[r][3];
        *(float4*)&OM[((size_t)bb * T_ + t) * D_ + h * 64 + c0] = o;
    }

    float pc4[4][4];
    #pragma unroll
    for (int r = 0; r < 4; ++r)
        #pragma unroll
        for (int c = 0; c < 4; ++c) pc4[r][c] = 0.f;
    for (int c = 0; c < 64; ++c) {
        float kr[4];
        #pragma unroll
        for (int r = 0; r < 4; ++r) kr[r] = ksT[i0 + r][c];
        float4 vv = *(const float4*)&vsn[c][c0];
        const float bc[4] = {vv.x, vv.y, vv.z, vv.w};
        #pragma unroll
        for (int r = 0; r < 4; ++r)
            #pragma unroll
            for (int cc = 0; cc < 4; ++cc)
                pc4[r][cc] = fmaf(kr[r], bc[cc], pc4[r][cc]);
    }
    #pragma unroll
    for (int r = 0; r < 4; ++r) {
        float4 o; o.x = pc4[r][0]; o.y = pc4[r][1]; o.z = pc4[r][2]; o.w = pc4[r][3];
        *(float4*)&CKV[(((size_t)bh) * N_ + n) * 4096 + (i0 + r) * 64 + c0] = o;
    }
}

// ---------------------------------------------------------------------------
// K3: in-place exclusive scan of CKV over chunks; writes FM (total) and FC.
// ---------------------------------------------------------------------------
__global__ __launch_bounds__(256)
void k_scan(float* __restrict__ CKV, float* __restrict__ FM, float* __restrict__ FC)
{
    const int bh = blockIdx.x >> 4;
    const int e  = (blockIdx.x & 15) * 256 + threadIdx.x;
    const size_t base = (size_t)bh * N_ * 4096 + e;
    float vals[64];
    #pragma unroll
    for (int nn = 0; nn < 64; ++nn) vals[nn] = CKV[base + (size_t)nn * 4096];
    float run = 0.f;
    #pragma unroll
    for (int nn = 0; nn < 64; ++nn) {
        CKV[base + (size_t)nn * 4096] = run;
        run += vals[nn];
    }
    FM[(size_t)bh * 4096 + e] = run;
    if ((blockIdx.x & 15) == 0 && threadIdx.x == 0) FC[bh] = (float)T_;
}

// ---------------------------------------------------------------------------
// K4: cross[i][dd] = sum_k q[i][k] prefix[k][dd]; OM = (intra+cross)/total.
// ---------------------------------------------------------------------------
__global__ __launch_bounds__(256)
void k_cross(const float* __restrict__ Q, const float* __restrict__ CKV,
             float* __restrict__ OM)
{
    __shared__ float qsT[64][64];
    __shared__ float ps[64][64];
    const int tid = threadIdx.x;
    const int bh = blockIdx.x >> 6, n = blockIdx.x & 63;
    const int tr = tid >> 4, tc = tid & 15;
    const int i0 = tr * 4, c0 = tc * 4;

    const float* qg = Q + ((size_t)bh * T_ + n * 64) * 64;
    #pragma unroll
    for (int p = 0; p < 4; ++p) {
        const int off = p * 1024 + tid * 4;
        float4 v = *(const float4*)(qg + off);
        const int row = off >> 6, col = off & 63;
        qsT[col+0][row] = v.x; qsT[col+1][row] = v.y;
        qsT[col+2][row] = v.z; qsT[col+3][row] = v.w;
    }
    const float* pg = CKV + ((size_t)bh * N_ + n) * 4096;
    #pragma unroll
    for (int p = 0; p < 4; ++p) {
        const int off = p * 1024 + tid * 4;
        *(float4*)(&ps[0][0] + off) = *(const float4*)(pg + off);
    }
    __syncthreads();

    float pa[4][4];
    #pragma unroll
    for (int r = 0; r < 4; ++r)
        #pragma unroll
        for (int c = 0; c < 4; ++c) pa[r][c] = 0.f;
    for (int k = 0; k < 64; ++k) {
        float4 qv = *(const float4*)&qsT[k][i0];
        float4 pv = *(const float4*)&ps[k][c0];
        const float ar[4] = {qv.x, qv.y, qv.z, qv.w};
        const float bc[4] = {pv.x, pv.y, pv.z, pv.w};
        #pragma unroll
        for (int r = 0; r < 4; ++r)
            #pragma unroll
            for (int c = 0; c < 4; ++c)
                pa[r][c] = fmaf(ar[r], bc[c], pa[r][c]);
    }
    const int bb = bh >> 4, h = bh & 15;
    #pragma unroll
    for (int r = 0; r < 4; ++r) {
        const int t = n * 64 + i0 + r;
        const float inv = 1.0f / (float)(t + 1);
        const size_t o = ((size_t)bb * T_ + t) * D_ + h * 64 + c0;
        float4 cur = *(float4*)&OM[o];
        cur.x = (cur.x + pa[r][0]) * inv;
        cur.y = (cur.y + pa[r][1]) * inv;
        cur.z = (cur.z + pa[r][2]) * inv;
        cur.w = (cur.w + pa[r][3]) * inv;
        *(float4*)&OM[o] = cur;
    }
}

extern "C" void kernel_launch(void* const* d_in, const int* in_sizes, int n_in,
                              void* d_out, int out_size, void* d_ws, size_t ws_size,
                              hipStream_t stream)
{
    const float* X    = (const float*)d_in[0];
    const float* Wqkv = (const float*)d_in[1];
    const float* Wo   = (const float*)d_in[2];

    float* Y  = (float*)d_out;                       // [B,T,D]
    float* FM = Y + (size_t)B_ * T_ * D_;            // [B,H,64,64]
    float* FC = FM + (size_t)B_ * H_ * HD_ * HD_;    // [B,H,1,1]

    char* ws = (char*)d_ws;
    float*       Q   = (float*)ws;                       // 64 MiB
    signed char* K8  = (signed char*)(ws + 67108864);    // 16 MiB
    signed char* V8  = (signed char*)(ws + 83886080);    // 16 MiB
    float*       CKV = (float*)(ws + 100663296);         // 64 MiB
    float*       OM  = (float*)(ws + 167772160);         // 64 MiB
    if (ws_size < (size_t)234881024) return;             // need 224 MiB scratch

    dim3 blk(256);
    k_gemm<0, 24><<<dim3(3072), blk, 0, stream>>>(X, Wqkv, Q, K8, V8, nullptr);
    k_chunk<<<dim3(4096), blk, 0, stream>>>(Q, K8, V8, OM, CKV);
    k_scan <<<dim3(1024), blk, 0, stream>>>(CKV, FM, FC);
    k_cross<<<dim3(4096), blk, 0, stream>>>(Q, CKV, OM);
    k_gemm<1, 8><<<dim3(1024), blk, 0, stream>>>(OM, Wo, nullptr, nullptr, nullptr, Y);
}

// Round 3
// 522.388 us; speedup vs baseline: 3.3031x; 1.4005x over previous
//
#include <hip/hip_runtime.h>
#include <cstdint>

// B=4, T=4096, D=1024, H=16, d=64, C=64, N=T/C=64
#define B_ 4
#define T_ 4096
#define D_ 1024
#define H_ 16
#define HD_ 64
#define N_ 64

typedef __attribute__((ext_vector_type(8))) short s16x8;
typedef __attribute__((ext_vector_type(4))) float f32x4;

__device__ __forceinline__ unsigned short f2bf(float f) {
    unsigned int u = __builtin_bit_cast(unsigned int, f);
    u += 0x7fffu + ((u >> 16) & 1u);          // RNE
    return (unsigned short)(u >> 16);
}
__device__ __forceinline__ float bf2f(unsigned short h) {
    unsigned int u = ((unsigned int)h) << 16;
    return __builtin_bit_cast(float, u);
}
__device__ __forceinline__ void gl2lds(const short* g, short* l) {
    __builtin_amdgcn_global_load_lds(
        (const __attribute__((address_space(1))) void*)g,
        (__attribute__((address_space(3))) void*)l, 16, 0, 0);
}

// ---------------------------------------------------------------------------
// Converters. k_cvt_split: fp32 -> interleaved (hi,lo) bf16 along K
// (out[2k]=hi(in[k]), out[2k+1]=lo). k_cvt: fp32 -> plain bf16.
// ---------------------------------------------------------------------------
__global__ __launch_bounds__(256)
void k_cvt_split(const float* __restrict__ in, short* __restrict__ out, int n4)
{
    int i = blockIdx.x * blockDim.x + threadIdx.x;
    const int stride = gridDim.x * blockDim.x;
    for (; i < n4; i += stride) {
        float4 f = ((const float4*)in)[i];
        const float v[4] = {f.x, f.y, f.z, f.w};
        s16x8 o;
        #pragma unroll
        for (int j = 0; j < 4; ++j) {
            unsigned short h = f2bf(v[j]);
            o[j*2]   = (short)h;
            o[j*2+1] = (short)f2bf(v[j] - bf2f(h));
        }
        ((s16x8*)out)[i] = o;
    }
}
__global__ __launch_bounds__(256)
void k_cvt(const float* __restrict__ in, short* __restrict__ out, int n4)
{
    int i = blockIdx.x * blockDim.x + threadIdx.x;
    const int stride = gridDim.x * blockDim.x;
    for (; i < n4; i += stride) {
        float4 f = ((const float4*)in)[i];
        short4 o;
        o.x = (short)f2bf(f.x); o.y = (short)f2bf(f.y);
        o.z = (short)f2bf(f.z); o.w = (short)f2bf(f.w);
        *(short4*)(out + i * 4) = o;
    }
}

// ---------------------------------------------------------------------------
// bf16 MFMA GEMM: O = A @ B^T. A [16384][KD], B [128*NCB][KD] bf16.
// 128x128 tile, BK=32, 4 waves (2x2), 16x16x32 MFMA.
// global_load_lds(16B) staging, double-buffered LDS, counted vmcnt(4),
// raw s_barriers (no full drain), XOR slot swizzle both sides.
// MODE 0: qkv epilogue (Q fp32 *0.125, K8/V8 sign). MODE 1: fp32 store Y.
// ---------------------------------------------------------------------------
template<int MODE, int KD, int NCB>
__global__ __launch_bounds__(256)
void k_gemm(const short* __restrict__ A, const short* __restrict__ Bm,
            float* __restrict__ OQ, signed char* __restrict__ K8,
            signed char* __restrict__ V8, float* __restrict__ Y)
{
    __shared__ __align__(16) short LS[2][2][128 * 32];

    const int tid = threadIdx.x;
    const int nwg = 128 * NCB;
    const int bid = blockIdx.x;
    const int sz  = (bid & 7) * (nwg >> 3) + (bid >> 3);   // XCD-contiguous
    const int cb  = sz % NCB, rb = sz / NCB;
    const int row0 = rb * 128, col0 = cb * 128;

    const int lane = tid & 63, w = tid >> 6;
    const int wr = w >> 1, wc = w & 1;

    // staging geometry: per wave 2 instr/matrix, each covers 16 rows x 32 cols
    const int srow = lane >> 2;                       // 0..15
    const int slog = (lane & 3) ^ ((lane >> 3) & 3);  // swizzled source slot
    const short* gA0 = A  + (size_t)(row0 + w * 32 +      srow) * KD + slog * 8;
    const short* gA1 = A  + (size_t)(row0 + w * 32 + 16 + srow) * KD + slog * 8;
    const short* gB0 = Bm + (size_t)(col0 + w * 32 +      srow) * KD + slog * 8;
    const short* gB1 = Bm + (size_t)(col0 + w * 32 + 16 + srow) * KD + slog * 8;

    // fragment read addressing (swizzled)
    const int cl = lane & 15, rg = lane >> 4;
    const int sph = rg ^ ((cl >> 1) & 3);
    const int fbA = (wr * 64 + cl) * 32 + sph * 8;
    const int fbB = (wc * 64 + cl) * 32 + sph * 8;

    f32x4 acc[4][4];
    #pragma unroll
    for (int i = 0; i < 4; ++i)
        #pragma unroll
        for (int j = 0; j < 4; ++j) acc[i][j] = (f32x4)0.f;

    auto stage = [&](int pb2, int t2) {
        const int ko = t2 * 32;
        gl2lds(gA0 + ko, &LS[pb2][0][(w * 32 +  0) * 32]);
        gl2lds(gA1 + ko, &LS[pb2][0][(w * 32 + 16) * 32]);
        gl2lds(gB0 + ko, &LS[pb2][1][(w * 32 +  0) * 32]);
        gl2lds(gB1 + ko, &LS[pb2][1][(w * 32 + 16) * 32]);
    };

    const int nt = KD / 32;
    stage(0, 0);
    for (int t = 0; t < nt; ++t) {
        const int pb = t & 1;
        if (t + 1 < nt) {
            stage(pb ^ 1, t + 1);
            asm volatile("s_waitcnt vmcnt(4)" ::: "memory");
        } else {
            asm volatile("s_waitcnt vmcnt(0)" ::: "memory");
        }
        __builtin_amdgcn_s_barrier();
        __builtin_amdgcn_sched_barrier(0);

        s16x8 fa[4], fb[4];
        #pragma unroll
        for (int mi = 0; mi < 4; ++mi)
            fa[mi] = *(const s16x8*)&LS[pb][0][fbA + mi * 512];
        #pragma unroll
        for (int ni = 0; ni < 4; ++ni)
            fb[ni] = *(const s16x8*)&LS[pb][1][fbB + ni * 512];

        asm volatile("s_waitcnt lgkmcnt(0)" ::: "memory");
        __builtin_amdgcn_sched_barrier(0);
        __builtin_amdgcn_s_barrier();

        #pragma unroll
        for (int ni = 0; ni < 4; ++ni)
            #pragma unroll
            for (int mi = 0; mi < 4; ++mi)
                acc[mi][ni] = __builtin_amdgcn_mfma_f32_16x16x32_bf16(
                    fa[mi], fb[ni], acc[mi][ni], 0, 0, 0);
    }

    const int m0 = row0 + wr * 64, n0 = col0 + wc * 64;
    if (MODE == 0) {
        const int s = col0 >> 10;               // 0:q 1:k 2:v, uniform/block
        #pragma unroll
        for (int ni = 0; ni < 4; ++ni) {
            const int col = n0 + ni * 16 + cl;
            const int h = (col & 1023) >> 6, dd = col & 63;
            #pragma unroll
            for (int mi = 0; mi < 4; ++mi)
                #pragma unroll
                for (int r = 0; r < 4; ++r) {
                    const int bt = m0 + mi * 16 + rg * 4 + r;
                    const int bb = bt >> 12, t = bt & (T_ - 1);
                    const size_t o = ((size_t)(bb * H_ + h) * T_ + t) * HD_ + dd;
                    const float v = acc[mi][ni][r];
                    if (s == 0)      OQ[o] = v * 0.125f;
                    else if (s == 1) K8[o] = v >= 0.f ? 1 : -1;
                    else             V8[o] = v >= 0.f ? 1 : -1;
                }
        }
    } else {
        #pragma unroll
        for (int ni = 0; ni < 4; ++ni) {
            const int col = n0 + ni * 16 + cl;
            #pragma unroll
            for (int mi = 0; mi < 4; ++mi)
                #pragma unroll
                for (int r = 0; r < 4; ++r)
                    Y[(size_t)(m0 + mi * 16 + rg * 4 + r) * D_ + col] = acc[mi][ni][r];
        }
    }
}

// ---------------------------------------------------------------------------
// K2: per chunk (b,h,n): intra = tril(q k^T) v  -> OM[b,t,h*64+dd]
//     and chunk_kv[kdim][dd] = sum_c k[c][kdim] v[c][dd] -> CKV.
// ---------------------------------------------------------------------------
__global__ __launch_bounds__(256)
void k_chunk(const float* __restrict__ Q, const signed char* __restrict__ K8,
             const signed char* __restrict__ V8, float* __restrict__ OM,
             float* __restrict__ CKV)
{
    __shared__ float qsT[64][64];
    __shared__ float ksT[64][64];
    __shared__ float vsn[64][64];
    __shared__ float ssT[64][64];
    const int tid = threadIdx.x;
    const int bh = blockIdx.x >> 6;
    const int n  = blockIdx.x & 63;
    const int tr = tid >> 4, tc = tid & 15;
    const int i0 = tr * 4, c0 = tc * 4;

    const float* qg = Q + ((size_t)bh * T_ + n * 64) * 64;
    #pragma unroll
    for (int p = 0; p < 4; ++p) {
        const int off = p * 1024 + tid * 4;
        float4 v = *(const float4*)(qg + off);
        const int row = off >> 6, col = off & 63;
        qsT[col+0][row] = v.x; qsT[col+1][row] = v.y;
        qsT[col+2][row] = v.z; qsT[col+3][row] = v.w;
    }
    {
        const signed char* kg = K8 + ((size_t)bh * T_ + n * 64) * 64;
        int4 kw = *(const int4*)(kg + tid * 16);
        const signed char* kc = (const signed char*)&kw;
        const int row = tid >> 2, colb = (tid & 3) * 16;
        #pragma unroll
        for (int c = 0; c < 16; ++c) ksT[colb + c][row] = (float)kc[c];

        const signed char* vg = V8 + ((size_t)bh * T_ + n * 64) * 64;
        int4 vw = *(const int4*)(vg + tid * 16);
        const signed char* vcp = (const signed char*)&vw;
        #pragma unroll
        for (int q4 = 0; q4 < 4; ++q4) {
            float4 t4;
            t4.x = (float)vcp[q4*4+0]; t4.y = (float)vcp[q4*4+1];
            t4.z = (float)vcp[q4*4+2]; t4.w = (float)vcp[q4*4+3];
            *(float4*)&vsn[row][colb + q4*4] = t4;
        }
    }
    __syncthreads();

    float pa[4][4];
    #pragma unroll
    for (int r = 0; r < 4; ++r)
        #pragma unroll
        for (int c = 0; c < 4; ++c) pa[r][c] = 0.f;
    for (int dd = 0; dd < 64; ++dd) {
        float4 qv = *(const float4*)&qsT[dd][i0];
        float4 kv = *(const float4*)&ksT[dd][c0];
        const float ar[4] = {qv.x, qv.y, qv.z, qv.w};
        const float bc[4] = {kv.x, kv.y, kv.z, kv.w};
        #pragma unroll
        for (int r = 0; r < 4; ++r)
            #pragma unroll
            for (int c = 0; c < 4; ++c)
                pa[r][c] = fmaf(ar[r], bc[c], pa[r][c]);
    }
    #pragma unroll
    for (int r = 0; r < 4; ++r)
        #pragma unroll
        for (int c = 0; c < 4; ++c) {
            const int i = i0 + r, j = c0 + c;
            ssT[j][i] = (j <= i) ? pa[r][c] : 0.f;
        }
    __syncthreads();

    float pb[4][4];
    #pragma unroll
    for (int r = 0; r < 4; ++r)
        #pragma unroll
        for (int c = 0; c < 4; ++c) pb[r][c] = 0.f;
    for (int j = 0; j < 64; ++j) {
        float4 sv = *(const float4*)&ssT[j][i0];
        float4 vv = *(const float4*)&vsn[j][c0];
        const float ar[4] = {sv.x, sv.y, sv.z, sv.w};
        const float bc[4] = {vv.x, vv.y, vv.z, vv.w};
        #pragma unroll
        for (int r = 0; r < 4; ++r)
            #pragma unroll
            for (int c = 0; c < 4; ++c)
                pb[r][c] = fmaf(ar[r], bc[c], pb[r][c]);
    }
    const int bb = bh >> 4, h = bh & 15;
    #pragma unroll
    for (int r = 0; r < 4; ++r) {
        const int t = n * 64 + i0 + r;
        float4 o; o.x = pb[r][0]; o.y = pb[r][1]; o.z = pb[r][2]; o.w = pb[r][3];
        *(float4*)&OM[((size_t)bb * T_ + t) * D_ + h * 64 + c0] = o;
    }

    float pc4[4][4];
    #pragma unroll
    for (int r = 0; r < 4; ++r)
        #pragma unroll
        for (int c = 0; c < 4; ++c) pc4[r][c] = 0.f;
    for (int c = 0; c < 64; ++c) {
        float kr[4];
        #pragma unroll
        for (int r = 0; r < 4; ++r) kr[r] = ksT[i0 + r][c];
        float4 vv = *(const float4*)&vsn[c][c0];
        const float bc[4] = {vv.x, vv.y, vv.z, vv.w};
        #pragma unroll
        for (int r = 0; r < 4; ++r)
            #pragma unroll
            for (int cc = 0; cc < 4; ++cc)
                pc4[r][cc] = fmaf(kr[r], bc[cc], pc4[r][cc]);
    }
    #pragma unroll
    for (int r = 0; r < 4; ++r) {
        float4 o; o.x = pc4[r][0]; o.y = pc4[r][1]; o.z = pc4[r][2]; o.w = pc4[r][3];
        *(float4*)&CKV[(((size_t)bh) * N_ + n) * 4096 + (i0 + r) * 64 + c0] = o;
    }
}

// ---------------------------------------------------------------------------
// K3: in-place exclusive scan of CKV over chunks; writes FM (total) and FC.
// ---------------------------------------------------------------------------
__global__ __launch_bounds__(256)
void k_scan(float* __restrict__ CKV, float* __restrict__ FM, float* __restrict__ FC)
{
    const int bh = blockIdx.x >> 4;
    const int e  = (blockIdx.x & 15) * 256 + threadIdx.x;
    const size_t base = (size_t)bh * N_ * 4096 + e;
    float vals[64];
    #pragma unroll
    for (int nn = 0; nn < 64; ++nn) vals[nn] = CKV[base + (size_t)nn * 4096];
    float run = 0.f;
    #pragma unroll
    for (int nn = 0; nn < 64; ++nn) {
        CKV[base + (size_t)nn * 4096] = run;
        run += vals[nn];
    }
    FM[(size_t)bh * 4096 + e] = run;
    if ((blockIdx.x & 15) == 0 && threadIdx.x == 0) FC[bh] = (float)T_;
}

// ---------------------------------------------------------------------------
// K4: cross[i][dd] = sum_k q[i][k] prefix[k][dd];
//     OMb = bf16((OM + cross) / total)  -> feeds the bf16 out-GEMM.
// ---------------------------------------------------------------------------
__global__ __launch_bounds__(256)
void k_cross(const float* __restrict__ Q, const float* __restrict__ CKV,
             const float* __restrict__ OM, short* __restrict__ OMb)
{
    __shared__ float qsT[64][64];
    __shared__ float ps[64][64];
    const int tid = threadIdx.x;
    const int bh = blockIdx.x >> 6, n = blockIdx.x & 63;
    const int tr = tid >> 4, tc = tid & 15;
    const int i0 = tr * 4, c0 = tc * 4;

    const float* qg = Q + ((size_t)bh * T_ + n * 64) * 64;
    #pragma unroll
    for (int p = 0; p < 4; ++p) {
        const int off = p * 1024 + tid * 4;
        float4 v = *(const float4*)(qg + off);
        const int row = off >> 6, col = off & 63;
        qsT[col+0][row] = v.x; qsT[col+1][row] = v.y;
        qsT[col+2][row] = v.z; qsT[col+3][row] = v.w;
    }
    const float* pg = CKV + ((size_t)bh * N_ + n) * 4096;
    #pragma unroll
    for (int p = 0; p < 4; ++p) {
        const int off = p * 1024 + tid * 4;
        *(float4*)(&ps[0][0] + off) = *(const float4*)(pg + off);
    }
    __syncthreads();

    float pa[4][4];
    #pragma unroll
    for (int r = 0; r < 4; ++r)
        #pragma unroll
        for (int c = 0; c < 4; ++c) pa[r][c] = 0.f;
    for (int k = 0; k < 64; ++k) {
        float4 qv = *(const float4*)&qsT[k][i0];
        float4 pv = *(const float4*)&ps[k][c0];
        const float ar[4] = {qv.x, qv.y, qv.z, qv.w};
        const float bc[4] = {pv.x, pv.y, pv.z, pv.w};
        #pragma unroll
        for (int r = 0; r < 4; ++r)
            #pragma unroll
            for (int c = 0; c < 4; ++c)
                pa[r][c] = fmaf(ar[r], bc[c], pa[r][c]);
    }
    const int bb = bh >> 4, h = bh & 15;
    #pragma unroll
    for (int r = 0; r < 4; ++r) {
        const int t = n * 64 + i0 + r;
        const float inv = 1.0f / (float)(t + 1);
        const size_t o = ((size_t)bb * T_ + t) * D_ + h * 64 + c0;
        float4 cur = *(const float4*)&OM[o];
        short4 q4;
        q4.x = (short)f2bf((cur.x + pa[r][0]) * inv);
        q4.y = (short)f2bf((cur.y + pa[r][1]) * inv);
        q4.z = (short)f2bf((cur.z + pa[r][2]) * inv);
        q4.w = (short)f2bf((cur.w + pa[r][3]) * inv);
        *(short4*)&OMb[o] = q4;
    }
}

extern "C" void kernel_launch(void* const* d_in, const int* in_sizes, int n_in,
                              void* d_out, int out_size, void* d_ws, size_t ws_size,
                              hipStream_t stream)
{
    const float* X    = (const float*)d_in[0];
    const float* Wqkv = (const float*)d_in[1];
    const float* Wo   = (const float*)d_in[2];

    float* Y  = (float*)d_out;                       // [B,T,D]
    float* FM = Y + (size_t)B_ * T_ * D_;            // [B,H,64,64]
    float* FC = FM + (size_t)B_ * H_ * HD_ * HD_;    // [B,H,1,1]

    char* ws = (char*)d_ws;
    // lifetimes: XS/WSq live only until qkv GEMM; OM overwrites XS;
    // CKV overwrites WSq; OMb overwrites K8/V8; WoS overwrites CKV.
    float*       Q   = (float*)ws;                       // 64 MiB @0
    signed char* K8  = (signed char*)(ws + 67108864);    // 16 MiB @64Mi
    signed char* V8  = (signed char*)(ws + 83886080);    // 16 MiB @80Mi
    short*       OMb = (short*)(ws + 67108864);          // 32 MiB @64Mi (late)
    float*       CKV = (float*)(ws + 100663296);         // 64 MiB @96Mi
    short*       WSq = (short*)(ws + 100663296);         // 12 MiB @96Mi (early)
    short*       WoS = (short*)(ws + 100663296);         //  2 MiB @96Mi (late)
    float*       OM  = (float*)(ws + 167772160);         // 64 MiB @160Mi
    short*       XS  = (short*)(ws + 167772160);         // 64 MiB @160Mi (early)
    if (ws_size < (size_t)234881024) return;             // need 224 MiB scratch

    dim3 blk(256);
    k_cvt_split<<<dim3(2048), blk, 0, stream>>>(X, XS, 4194304);
    k_cvt_split<<<dim3(1024), blk, 0, stream>>>(Wqkv, WSq, 786432);
    k_gemm<0, 2048, 24><<<dim3(3072), blk, 0, stream>>>(XS, WSq, Q, K8, V8, nullptr);
    k_chunk<<<dim3(4096), blk, 0, stream>>>(Q, K8, V8, OM, CKV);
    k_scan <<<dim3(1024), blk, 0, stream>>>(CKV, FM, FC);
    k_cross<<<dim3(4096), blk, 0, stream>>>(Q, CKV, OM, OMb);
    k_cvt<<<dim3(512), blk, 0, stream>>>(Wo, WoS, 262144);
    k_gemm<1, 1024, 8><<<dim3(1024), blk, 0, stream>>>(OMb, WoS, nullptr, nullptr, nullptr, Y);
}

// Round 4
// 429.727 us; speedup vs baseline: 4.0154x; 1.2156x over previous
//
#include <hip/hip_runtime.h>
#include <cstdint>

// B=4, T=4096, D=1024, H=16, d=64, C=64, N=T/C=64
#define B_ 4
#define T_ 4096
#define D_ 1024
#define H_ 16
#define HD_ 64
#define N_ 64

typedef __attribute__((ext_vector_type(8))) short s16x8;
typedef __attribute__((ext_vector_type(4))) float f32x4;

__device__ __forceinline__ unsigned short f2bf(float f) {
    unsigned int u = __builtin_bit_cast(unsigned int, f);
    u += 0x7fffu + ((u >> 16) & 1u);          // RNE
    return (unsigned short)(u >> 16);
}
__device__ __forceinline__ float bf2f(unsigned short h) {
    unsigned int u = ((unsigned int)h) << 16;
    return __builtin_bit_cast(float, u);
}
__device__ __forceinline__ void gl2lds(const short* g, short* l) {
    __builtin_amdgcn_global_load_lds(
        (const __attribute__((address_space(1))) void*)g,
        (__attribute__((address_space(3))) void*)l, 16, 0, 0);
}
#define MFMA16(a, b, c) __builtin_amdgcn_mfma_f32_16x16x32_bf16(a, b, c, 0, 0, 0)

// ---------------------------------------------------------------------------
// Converters.
// ---------------------------------------------------------------------------
__global__ __launch_bounds__(256)
void k_cvt_split(const float* __restrict__ in, short* __restrict__ out, int n4)
{
    int i = blockIdx.x * blockDim.x + threadIdx.x;
    const int stride = gridDim.x * blockDim.x;
    for (; i < n4; i += stride) {
        float4 f = ((const float4*)in)[i];
        const float v[4] = {f.x, f.y, f.z, f.w};
        s16x8 o;
        #pragma unroll
        for (int j = 0; j < 4; ++j) {
            unsigned short h = f2bf(v[j]);
            o[j*2]   = (short)h;
            o[j*2+1] = (short)f2bf(v[j] - bf2f(h));
        }
        ((s16x8*)out)[i] = o;
    }
}
__global__ __launch_bounds__(256)
void k_cvt(const float* __restrict__ in, short* __restrict__ out, int n4)
{
    int i = blockIdx.x * blockDim.x + threadIdx.x;
    const int stride = gridDim.x * blockDim.x;
    for (; i < n4; i += stride) {
        float4 f = ((const float4*)in)[i];
        short4 o;
        o.x = (short)f2bf(f.x); o.y = (short)f2bf(f.y);
        o.z = (short)f2bf(f.z); o.w = (short)f2bf(f.w);
        *(short4*)(out + i * 4) = o;
    }
}

// ---------------------------------------------------------------------------
// bf16 MFMA GEMM: O = A @ B^T. A [16384][KD], B [128*NCB][KD] bf16.
// 128x128 tile, BK=32, 4 waves (2x2), 16x16x32 MFMA, gl2lds staging,
// double-buffered LDS, counted vmcnt(4), XOR slot swizzle both sides.
// MODE 0: k/v epilogue (sign bf16 -> Kb+KbT or VbT). MODE 1: fp32 Y.
// MODE 2: Q epilogue (bf16, *0.125).
// ---------------------------------------------------------------------------
template<int MODE, int KD, int NCB>
__global__ __launch_bounds__(256)
void k_gemm(const short* __restrict__ A, const short* __restrict__ Bm,
            short* __restrict__ O1, short* __restrict__ O2,
            short* __restrict__ O3, float* __restrict__ Yf)
{
    __shared__ __align__(16) short LS[2][2][128 * 32];

    const int tid = threadIdx.x;
    const int nwg = 128 * NCB;
    const int bid = blockIdx.x;
    const int sz  = (bid & 7) * (nwg >> 3) + (bid >> 3);   // XCD-contiguous
    const int cb  = sz % NCB, rb = sz / NCB;
    const int row0 = rb * 128, col0 = cb * 128;

    const int lane = tid & 63, w = tid >> 6;
    const int wr = w >> 1, wc = w & 1;

    const int srow = lane >> 2;                       // 0..15
    const int slog = (lane & 3) ^ ((lane >> 3) & 3);  // swizzled source slot
    const short* gA0 = A  + (size_t)(row0 + w * 32 +      srow) * KD + slog * 8;
    const short* gA1 = A  + (size_t)(row0 + w * 32 + 16 + srow) * KD + slog * 8;
    const short* gB0 = Bm + (size_t)(col0 + w * 32 +      srow) * KD + slog * 8;
    const short* gB1 = Bm + (size_t)(col0 + w * 32 + 16 + srow) * KD + slog * 8;

    const int cl = lane & 15, rg = lane >> 4;
    const int sph = rg ^ ((cl >> 1) & 3);
    const int fbA = (wr * 64 + cl) * 32 + sph * 8;
    const int fbB = (wc * 64 + cl) * 32 + sph * 8;

    f32x4 acc[4][4];
    #pragma unroll
    for (int i = 0; i < 4; ++i)
        #pragma unroll
        for (int j = 0; j < 4; ++j) acc[i][j] = (f32x4)0.f;

    auto stage = [&](int pb2, int t2) {
        const int ko = t2 * 32;
        gl2lds(gA0 + ko, &LS[pb2][0][(w * 32 +  0) * 32]);
        gl2lds(gA1 + ko, &LS[pb2][0][(w * 32 + 16) * 32]);
        gl2lds(gB0 + ko, &LS[pb2][1][(w * 32 +  0) * 32]);
        gl2lds(gB1 + ko, &LS[pb2][1][(w * 32 + 16) * 32]);
    };

    const int nt = KD / 32;
    stage(0, 0);
    for (int t = 0; t < nt; ++t) {
        const int pb = t & 1;
        if (t + 1 < nt) {
            stage(pb ^ 1, t + 1);
            asm volatile("s_waitcnt vmcnt(4)" ::: "memory");
        } else {
            asm volatile("s_waitcnt vmcnt(0)" ::: "memory");
        }
        __builtin_amdgcn_s_barrier();
        __builtin_amdgcn_sched_barrier(0);

        s16x8 fa[4], fb[4];
        #pragma unroll
        for (int mi = 0; mi < 4; ++mi)
            fa[mi] = *(const s16x8*)&LS[pb][0][fbA + mi * 512];
        #pragma unroll
        for (int ni = 0; ni < 4; ++ni)
            fb[ni] = *(const s16x8*)&LS[pb][1][fbB + ni * 512];

        asm volatile("s_waitcnt lgkmcnt(0)" ::: "memory");
        __builtin_amdgcn_sched_barrier(0);
        __builtin_amdgcn_s_barrier();

        #pragma unroll
        for (int ni = 0; ni < 4; ++ni)
            #pragma unroll
            for (int mi = 0; mi < 4; ++mi)
                acc[mi][ni] = MFMA16(fa[mi], fb[ni], acc[mi][ni]);
    }

    const int m0 = row0 + wr * 64, n0 = col0 + wc * 64;
    if (MODE == 0) {
        const int s = 1 + (col0 >> 10);       // 1:k 2:v, uniform per block
        #pragma unroll
        for (int ni = 0; ni < 4; ++ni) {
            const int col = n0 + ni * 16 + cl;
            const int h = (col & 1023) >> 6, dd = col & 63;
            #pragma unroll
            for (int mi = 0; mi < 4; ++mi)
                #pragma unroll
                for (int r = 0; r < 4; ++r) {
                    const int bt = m0 + mi * 16 + rg * 4 + r;
                    const int bb = bt >> 12, t = bt & (T_ - 1);
                    const size_t bh64 = (size_t)(bb * H_ + h);
                    const short sg = (acc[mi][ni][r] >= 0.f) ? (short)0x3F80
                                                             : (short)0xBF80;
                    const size_t otr = bh64 * ((size_t)T_ * 64)
                                     + (size_t)(t >> 6) * 4096 + dd * 64 + (t & 63);
                    if (s == 1) {
                        O1[(bh64 * T_ + t) * 64 + dd] = sg;   // Kb [c][d]
                        O2[otr] = sg;                         // KbT [d][c]
                    } else {
                        O3[otr] = sg;                         // VbT [d][c]
                    }
                }
        }
    } else if (MODE == 2) {
        #pragma unroll
        for (int ni = 0; ni < 4; ++ni) {
            const int col = n0 + ni * 16 + cl;
            const int h = col >> 6, dd = col & 63;
            #pragma unroll
            for (int mi = 0; mi < 4; ++mi)
                #pragma unroll
                for (int r = 0; r < 4; ++r) {
                    const int bt = m0 + mi * 16 + rg * 4 + r;
                    const int bb = bt >> 12, t = bt & (T_ - 1);
                    O1[((size_t)(bb * H_ + h) * T_ + t) * 64 + dd] =
                        (short)f2bf(acc[mi][ni][r] * 0.125f);
                }
        }
    } else {
        #pragma unroll
        for (int ni = 0; ni < 4; ++ni) {
            const int col = n0 + ni * 16 + cl;
            #pragma unroll
            for (int mi = 0; mi < 4; ++mi)
                #pragma unroll
                for (int r = 0; r < 4; ++r)
                    Yf[(size_t)(m0 + mi * 16 + rg * 4 + r) * D_ + col] =
                        acc[mi][ni][r];
        }
    }
}

// ---------------------------------------------------------------------------
// K2 (MFMA): per chunk: S = mask(Q K^T); intra = S V^T-op -> OMi bf16;
// ckvT[dd][kd] = sum_c v[c][dd] k[c][kd] -> CKV8 int8 (exact small ints).
// All LDS tiles 64x64 bf16, XOR-swizzled, B^T fragment convention.
// ---------------------------------------------------------------------------
__global__ __launch_bounds__(256)
void k_chunk2(const short* __restrict__ Qb, const short* __restrict__ Kb,
              const short* __restrict__ KbT, const short* __restrict__ VbT,
              short* __restrict__ OMi, signed char* __restrict__ CKV8)
{
    __shared__ __align__(16) short Qs[4096], Ks[4096], KTs[4096], VTs[4096], Ss[4096];
    const int tid = threadIdx.x;
    const int bh = blockIdx.x >> 6, n = blockIdx.x & 63;
    const size_t cbase = ((size_t)bh * T_ + n * 64) * 64;

    auto stage_tile = [&](const short* g, short* l) {
        #pragma unroll
        for (int p = 0; p < 2; ++p) {
            const int off = tid * 16 + p * 4096;
            const int r = off >> 7;
            s16x8 v = *(const s16x8*)(g + (off >> 1));
            *(s16x8*)((char*)l + (off ^ ((r & 7) << 4))) = v;
        }
    };
    stage_tile(Qb  + cbase, Qs);
    stage_tile(Kb  + cbase, Ks);
    stage_tile(KbT + cbase, KTs);
    stage_tile(VbT + cbase, VTs);
    __syncthreads();

    const int lane = tid & 63, w = tid >> 6;
    const int cl = lane & 15, rg = lane >> 4;

    auto frag = [&](const short* l, int rowbase, int kk) -> s16x8 {
        const int row = rowbase + cl;
        int off = row * 128 + kk * 64 + rg * 16;
        off ^= (row & 7) << 4;
        return *(const s16x8*)((const char*)l + off);
    };

    // phase 1: S = Q K^T (masked), bf16 -> Ss
    {
        f32x4 a1[4];
        #pragma unroll
        for (int ni = 0; ni < 4; ++ni) a1[ni] = (f32x4)0.f;
        const s16x8 qa0 = frag(Qs, w * 16, 0), qa1 = frag(Qs, w * 16, 1);
        #pragma unroll
        for (int ni = 0; ni < 4; ++ni) {
            a1[ni] = MFMA16(qa0, frag(Ks, ni * 16, 0), a1[ni]);
            a1[ni] = MFMA16(qa1, frag(Ks, ni * 16, 1), a1[ni]);
        }
        #pragma unroll
        for (int ni = 0; ni < 4; ++ni)
            #pragma unroll
            for (int r = 0; r < 4; ++r) {
                const int i = w * 16 + rg * 4 + r, j = ni * 16 + cl;
                const float v = (j <= i) ? a1[ni][r] : 0.f;
                const int off = (i * 128 + j * 2) ^ ((i & 7) << 4);
                *(short*)((char*)Ss + off) = (short)f2bf(v);
            }
    }
    __syncthreads();

    // phase 2: intra = S * V  (B-op = VT rows = dd)
    // phase 3: ckvT[dd][kd]   (A = VT rows dd, B = KT rows kd)
    f32x4 a2[4], a3[4];
    #pragma unroll
    for (int ni = 0; ni < 4; ++ni) { a2[ni] = (f32x4)0.f; a3[ni] = (f32x4)0.f; }
    {
        const s16x8 sa0 = frag(Ss, w * 16, 0),  sa1 = frag(Ss, w * 16, 1);
        const s16x8 va0 = frag(VTs, w * 16, 0), va1 = frag(VTs, w * 16, 1);
        #pragma unroll
        for (int ni = 0; ni < 4; ++ni) {
            a2[ni] = MFMA16(sa0, frag(VTs, ni * 16, 0), a2[ni]);
            a2[ni] = MFMA16(sa1, frag(VTs, ni * 16, 1), a2[ni]);
            a3[ni] = MFMA16(va0, frag(KTs, ni * 16, 0), a3[ni]);
            a3[ni] = MFMA16(va1, frag(KTs, ni * 16, 1), a3[ni]);
        }
    }
    // stage intra (bf16, swizzled) into Qs; ckv (i8, linear) into Ks bytes
    #pragma unroll
    for (int ni = 0; ni < 4; ++ni)
        #pragma unroll
        for (int r = 0; r < 4; ++r) {
            const int m = w * 16 + rg * 4 + r;     // i for intra, dd for ckv
            const int c = ni * 16 + cl;            // dd for intra, kd for ckv
            const int off = (m * 128 + c * 2) ^ ((m & 7) << 4);
            *(short*)((char*)Qs + off) = (short)f2bf(a2[ni][r]);
            ((signed char*)Ks)[m * 64 + c] = (signed char)(int)a3[ni][r];
        }
    __syncthreads();

    // coalesced stores
    const int bb = bh >> 4, h = bh & 15;
    #pragma unroll
    for (int p = 0; p < 2; ++p) {
        const int off = tid * 16 + p * 4096;
        const int r = off >> 7;                    // c within chunk
        const int lo = off ^ ((r & 7) << 4);
        s16x8 v = *(const s16x8*)((char*)Qs + lo);
        const size_t gi = ((size_t)bb * T_ + n * 64 + r) * D_
                        + h * 64 + ((off & 127) >> 1);
        *(s16x8*)(OMi + gi) = v;
    }
    {
        const size_t c8 = ((size_t)bh * 64 + n) * 4096;
        *(int4*)(CKV8 + c8 + tid * 16) = *(const int4*)((const char*)Ks + tid * 16);
    }
}

// ---------------------------------------------------------------------------
// K3: integer exclusive scan of CKV8 over chunks -> PB bf16; FM fp32 exact.
// CKV8/PB layout per (bh,n): [dd][kd]; FM wants [kd][dd] -> transposed write.
// ---------------------------------------------------------------------------
__global__ __launch_bounds__(256)
void k_scan2(const signed char* __restrict__ CKV8, short* __restrict__ PB,
             float* __restrict__ FM, float* __restrict__ FC)
{
    const int bh = blockIdx.x >> 4;
    const int e  = (blockIdx.x & 15) * 256 + threadIdx.x;   // dd*64+kd
    const size_t b8 = (size_t)bh * N_ * 4096 + e;
    const size_t bp = (size_t)bh * N_ * 4096 + e;
    int run = 0;
    #pragma unroll
    for (int nn = 0; nn < 64; ++nn) {
        PB[bp + (size_t)nn * 4096] = (short)f2bf((float)run);
        run += (int)CKV8[b8 + (size_t)nn * 4096];
    }
    FM[(size_t)bh * 4096 + (e & 63) * 64 + (e >> 6)] = (float)run;
    if ((blockIdx.x & 15) == 0 && threadIdx.x == 0) FC[bh] = (float)T_;
}

// ---------------------------------------------------------------------------
// K4 (MFMA): cross = Q @ prefix (B-op = PB rows dd over K=d);
// OMb = bf16((OMi + cross) / total).
// ---------------------------------------------------------------------------
__global__ __launch_bounds__(256)
void k_cross2(const short* __restrict__ Qb, const short* __restrict__ PB,
              const short* __restrict__ OMi, short* __restrict__ OMb)
{
    __shared__ __align__(16) short Qs[4096], Ps[4096], Cs[4096];
    const int tid = threadIdx.x;
    const int bh = blockIdx.x >> 6, n = blockIdx.x & 63;
    const size_t cbase = ((size_t)bh * T_ + n * 64) * 64;

    auto stage_tile = [&](const short* g, short* l) {
        #pragma unroll
        for (int p = 0; p < 2; ++p) {
            const int off = tid * 16 + p * 4096;
            const int r = off >> 7;
            s16x8 v = *(const s16x8*)(g + (off >> 1));
            *(s16x8*)((char*)l + (off ^ ((r & 7) << 4))) = v;
        }
    };
    stage_tile(Qb + cbase, Qs);
    stage_tile(PB + ((size_t)bh * 64 + n) * 4096, Ps);
    __syncthreads();

    const int lane = tid & 63, w = tid >> 6;
    const int cl = lane & 15, rg = lane >> 4;

    auto frag = [&](const short* l, int rowbase, int kk) -> s16x8 {
        const int row = rowbase + cl;
        int off = row * 128 + kk * 64 + rg * 16;
        off ^= (row & 7) << 4;
        return *(const s16x8*)((const char*)l + off);
    };

    f32x4 a1[4];
    #pragma unroll
    for (int ni = 0; ni < 4; ++ni) a1[ni] = (f32x4)0.f;
    const s16x8 qa0 = frag(Qs, w * 16, 0), qa1 = frag(Qs, w * 16, 1);
    #pragma unroll
    for (int ni = 0; ni < 4; ++ni) {
        a1[ni] = MFMA16(qa0, frag(Ps, ni * 16, 0), a1[ni]);
        a1[ni] = MFMA16(qa1, frag(Ps, ni * 16, 1), a1[ni]);
    }
    #pragma unroll
    for (int ni = 0; ni < 4; ++ni)
        #pragma unroll
        for (int r = 0; r < 4; ++r) {
            const int i = w * 16 + rg * 4 + r, j = ni * 16 + cl;
            const int off = (i * 128 + j * 2) ^ ((i & 7) << 4);
            *(short*)((char*)Cs + off) = (short)f2bf(a1[ni][r]);
        }
    __syncthreads();

    const int bb = bh >> 4, h = bh & 15;
    #pragma unroll
    for (int p = 0; p < 2; ++p) {
        const int off = tid * 16 + p * 4096;
        const int r = off >> 7;                    // c within chunk
        const int lo = off ^ ((r & 7) << 4);
        s16x8 cv = *(const s16x8*)((char*)Cs + lo);
        const size_t gi = ((size_t)bb * T_ + n * 64 + r) * D_
                        + h * 64 + ((off & 127) >> 1);
        s16x8 iv = *(const s16x8*)(OMi + gi);
        const float invt = 1.0f / (float)(n * 64 + r + 1);
        s16x8 ov;
        #pragma unroll
        for (int j = 0; j < 8; ++j) {
            const float f = (bf2f((unsigned short)iv[j])
                           + bf2f((unsigned short)cv[j])) * invt;
            ov[j] = (short)f2bf(f);
        }
        *(s16x8*)(OMb + gi) = ov;
    }
}

extern "C" void kernel_launch(void* const* d_in, const int* in_sizes, int n_in,
                              void* d_out, int out_size, void* d_ws, size_t ws_size,
                              hipStream_t stream)
{
    const float* X    = (const float*)d_in[0];
    const float* Wqkv = (const float*)d_in[1];
    const float* Wo   = (const float*)d_in[2];

    float* Y  = (float*)d_out;                       // [B,T,D]
    float* FM = Y + (size_t)B_ * T_ * D_;            // [B,H,64,64]
    float* FC = FM + (size_t)B_ * H_ * HD_ * HD_;    // [B,H,1,1]

    char* ws = (char*)d_ws;
    const size_t Mi = 1048576;
    short*       Qb   = (short*)(ws + 0 * Mi);     // 32 MiB
    short*       Kb   = (short*)(ws + 32 * Mi);    // 32 MiB
    short*       KbT  = (short*)(ws + 64 * Mi);    // 32 MiB (early)
    short*       PB   = (short*)(ws + 64 * Mi);    // 32 MiB (late, over KbT)
    short*       VbT  = (short*)(ws + 96 * Mi);    // 32 MiB
    short*       XS   = (short*)(ws + 128 * Mi);   // 64 MiB (early)
    short*       Xb   = (short*)(ws + 128 * Mi);   // 32 MiB (mid, over XS)
    short*       OMi  = (short*)(ws + 128 * Mi);   // 32 MiB (late, over Xb)
    short*       OMb  = (short*)(ws + 160 * Mi);   // 32 MiB
    short*       WSq  = (short*)(ws + 192 * Mi);   //  8 MiB (early)
    signed char* CKV8 = (signed char*)(ws + 192 * Mi); // 16 MiB (late)
    short*       Wqb  = (short*)(ws + 208 * Mi);   //  2 MiB
    short*       WoS  = (short*)(ws + 210 * Mi);   //  2 MiB
    if (ws_size < (size_t)222 * Mi) return;

    dim3 blk(256);
    // X (split) and W_kv (split, rows 1024..3071 of Wqkv)
    k_cvt_split<<<dim3(2048), blk, 0, stream>>>(X, XS, 4194304);
    k_cvt_split<<<dim3(1024), blk, 0, stream>>>(Wqkv + (size_t)1024 * 1024, WSq, 524288);
    // K/V GEMM: split K=2048, N=2048
    k_gemm<0, 2048, 16><<<dim3(2048), blk, 0, stream>>>(XS, WSq, Kb, KbT, VbT, nullptr);
    // Q GEMM: plain bf16 K=1024 (Xb overwrites XS after kv-GEMM done)
    k_cvt<<<dim3(2048), blk, 0, stream>>>(X, Xb, 4194304);
    k_cvt<<<dim3(512),  blk, 0, stream>>>(Wqkv, Wqb, 262144);
    k_gemm<2, 1024, 8><<<dim3(1024), blk, 0, stream>>>(Xb, Wqb, Qb, nullptr, nullptr, nullptr);
    // chunk-local MFMA work
    k_chunk2<<<dim3(4096), blk, 0, stream>>>(Qb, Kb, KbT, VbT, OMi, CKV8);
    k_scan2 <<<dim3(1024), blk, 0, stream>>>(CKV8, PB, FM, FC);
    k_cross2<<<dim3(4096), blk, 0, stream>>>(Qb, PB, OMi, OMb);
    // output GEMM
    k_cvt<<<dim3(512), blk, 0, stream>>>(Wo, WoS, 262144);
    k_gemm<1, 1024, 8><<<dim3(1024), blk, 0, stream>>>(OMb, WoS, nullptr, nullptr, nullptr, Y);
}

// Round 5
// 380.178 us; speedup vs baseline: 4.5387x; 1.1303x over previous
//
#include <hip/hip_runtime.h>
#include <cstdint>

// B=4, T=4096, D=1024, H=16, d=64, C=64, N=T/C=64
#define B_ 4
#define T_ 4096
#define D_ 1024
#define H_ 16
#define HD_ 64
#define N_ 64

typedef __attribute__((ext_vector_type(8))) short s16x8;
typedef __attribute__((ext_vector_type(4))) float f32x4;

__device__ __forceinline__ unsigned short f2bf(float f) {
    unsigned int u = __builtin_bit_cast(unsigned int, f);
    u += 0x7fffu + ((u >> 16) & 1u);          // RNE
    return (unsigned short)(u >> 16);
}
__device__ __forceinline__ float bf2f(unsigned short h) {
    unsigned int u = ((unsigned int)h) << 16;
    return __builtin_bit_cast(float, u);
}
__device__ __forceinline__ void gl2lds(const short* g, short* l) {
    __builtin_amdgcn_global_load_lds(
        (const __attribute__((address_space(1))) void*)g,
        (__attribute__((address_space(3))) void*)l, 16, 0, 0);
}
#define MFMA16(a, b, c) __builtin_amdgcn_mfma_f32_16x16x32_bf16(a, b, c, 0, 0, 0)

// ---------------------------------------------------------------------------
// Converters.
// ---------------------------------------------------------------------------
__global__ __launch_bounds__(256)
void k_cvt_split(const float* __restrict__ in, short* __restrict__ out, int n4)
{
    int i = blockIdx.x * blockDim.x + threadIdx.x;
    const int stride = gridDim.x * blockDim.x;
    for (; i < n4; i += stride) {
        float4 f = ((const float4*)in)[i];
        const float v[4] = {f.x, f.y, f.z, f.w};
        s16x8 o;
        #pragma unroll
        for (int j = 0; j < 4; ++j) {
            unsigned short h = f2bf(v[j]);
            o[j*2]   = (short)h;
            o[j*2+1] = (short)f2bf(v[j] - bf2f(h));
        }
        ((s16x8*)out)[i] = o;
    }
}
__global__ __launch_bounds__(256)
void k_cvt(const float* __restrict__ in, short* __restrict__ out, int n4)
{
    int i = blockIdx.x * blockDim.x + threadIdx.x;
    const int stride = gridDim.x * blockDim.x;
    for (; i < n4; i += stride) {
        float4 f = ((const float4*)in)[i];
        short4 o;
        o.x = (short)f2bf(f.x); o.y = (short)f2bf(f.y);
        o.z = (short)f2bf(f.z); o.w = (short)f2bf(f.w);
        *(short4*)(out + i * 4) = o;
    }
}

// ---------------------------------------------------------------------------
// bf16 MFMA GEMM: O = A @ B^T. A [16384][KD], B [256*NCB][KD] bf16.
// 256x256 tile, BK=64, 512 threads (8 waves, 2x4), 16x16x32 MFMA.
// gl2lds staging (pre-swizzled global src, linear LDS dest), double-buffered
// 128 KiB LDS, counted vmcnt(8), reads+MFMA share one barrier region so
// waves overlap LDS and MFMA pipes. XOR slot swizzle: phys = logical^(row&7)
// on 128B rows (rows r,r+8 alias -> 2-way = free).
// MODE 0: k/v epilogue (sign bf16 -> Kb+KbT or VbT). MODE 1: fp32 Y.
// MODE 2: Q epilogue (bf16, *0.125).
// ---------------------------------------------------------------------------
template<int MODE, int KD, int NCB>
__global__ __launch_bounds__(512, 2)
void k_gemm(const short* __restrict__ A, const short* __restrict__ Bm,
            short* __restrict__ O1, short* __restrict__ O2,
            short* __restrict__ O3, float* __restrict__ Yf)
{
    __shared__ __align__(16) short LS[2][2][16384];   // [dbuf][A/B][256*64]

    const int tid = threadIdx.x;
    const int nwg = 64 * NCB;                          // (16384/256)*NCB
    const int bid = blockIdx.x;
    const int sz  = (bid & 7) * (nwg >> 3) + (bid >> 3);   // XCD-contiguous
    const int cb  = sz % NCB, rb = sz / NCB;
    const int row0 = rb * 256, col0 = cb * 256;

    const int lane = tid & 63, w = tid >> 6;
    const int wr = w >> 2, wc = w & 3;
    const int cl = lane & 15, rg = lane >> 4;

    // staging: wave w owns 32 rows of each tile; 4 calls x 8 rows, lane
    // l -> row (l>>3), phys slot (l&7); global src slot = (l&7)^(l>>3).
    const int sr8 = lane >> 3;
    const int slg = ((lane & 7) ^ sr8) * 8;
    const short* gA = A  + (size_t)(row0 + w * 32 + sr8) * KD + slg;
    const short* gB = Bm + (size_t)(col0 + w * 32 + sr8) * KD + slg;

    f32x4 acc[8][4];
    #pragma unroll
    for (int i = 0; i < 8; ++i)
        #pragma unroll
        for (int j = 0; j < 4; ++j) acc[i][j] = (f32x4)0.f;

    auto stage = [&](int pb2, int t2) {
        const int ko = t2 * 64;
        #pragma unroll
        for (int c = 0; c < 4; ++c) {
            gl2lds(gA + ko + c * 8 * KD, &LS[pb2][0][(w * 32 + c * 8) * 64]);
            gl2lds(gB + ko + c * 8 * KD, &LS[pb2][1][(w * 32 + c * 8) * 64]);
        }
    };
    // swizzled fragment read: logical slot q (0..7) of row R
    auto ldrd = [&](const short* base, int R, int q) -> s16x8 {
        const int off = R * 128 + (((q) ^ (R & 7)) << 4);
        return *(const s16x8*)((const char*)base + off);
    };

    const int nt = KD / 64;
    stage(0, 0);
    for (int t = 0; t < nt; ++t) {
        const int pb = t & 1;
        if (t + 1 < nt) {
            stage(pb ^ 1, t + 1);
            asm volatile("s_waitcnt vmcnt(8)" ::: "memory");
        } else {
            asm volatile("s_waitcnt vmcnt(0)" ::: "memory");
        }
        __builtin_amdgcn_s_barrier();
        __builtin_amdgcn_sched_barrier(0);

        const short* bA = &LS[pb][0][0];
        const short* bB = &LS[pb][1][0];
        s16x8 fb[2][4];
        #pragma unroll
        for (int kk = 0; kk < 2; ++kk)
            #pragma unroll
            for (int ni = 0; ni < 4; ++ni)
                fb[kk][ni] = ldrd(bB, wc * 64 + ni * 16 + cl, kk * 4 + rg);
        s16x8 fa[8];
        #pragma unroll
        for (int mi = 0; mi < 8; ++mi)
            fa[mi] = ldrd(bA, wr * 128 + mi * 16 + cl, rg);

        __builtin_amdgcn_s_setprio(1);
        #pragma unroll
        for (int ni = 0; ni < 4; ++ni)
            #pragma unroll
            for (int mi = 0; mi < 8; ++mi)
                acc[mi][ni] = MFMA16(fa[mi], fb[0][ni], acc[mi][ni]);
        __builtin_amdgcn_s_setprio(0);

        #pragma unroll
        for (int mi = 0; mi < 8; ++mi)
            fa[mi] = ldrd(bA, wr * 128 + mi * 16 + cl, 4 + rg);

        __builtin_amdgcn_s_setprio(1);
        #pragma unroll
        for (int ni = 0; ni < 4; ++ni)
            #pragma unroll
            for (int mi = 0; mi < 8; ++mi)
                acc[mi][ni] = MFMA16(fa[mi], fb[1][ni], acc[mi][ni]);
        __builtin_amdgcn_s_setprio(0);

        asm volatile("s_waitcnt lgkmcnt(0)" ::: "memory");
        __builtin_amdgcn_sched_barrier(0);
        __builtin_amdgcn_s_barrier();
    }

    const int m0 = row0 + wr * 128, n0 = col0 + wc * 64;
    if (MODE == 0) {
        const int s = 1 + (col0 >> 10);       // 1:k 2:v, uniform per block
        #pragma unroll
        for (int ni = 0; ni < 4; ++ni) {
            const int col = n0 + ni * 16 + cl;
            const int h = (col & 1023) >> 6, dd = col & 63;
            #pragma unroll
            for (int mi = 0; mi < 8; ++mi)
                #pragma unroll
                for (int r = 0; r < 4; ++r) {
                    const int bt = m0 + mi * 16 + rg * 4 + r;
                    const int bb = bt >> 12, t = bt & (T_ - 1);
                    const size_t bh64 = (size_t)(bb * H_ + h);
                    const short sg = (acc[mi][ni][r] >= 0.f) ? (short)0x3F80
                                                             : (short)0xBF80;
                    const size_t otr = bh64 * ((size_t)T_ * 64)
                                     + (size_t)(t >> 6) * 4096 + dd * 64 + (t & 63);
                    if (s == 1) {
                        O1[(bh64 * T_ + t) * 64 + dd] = sg;   // Kb [c][d]
                        O2[otr] = sg;                         // KbT [d][c]
                    } else {
                        O3[otr] = sg;                         // VbT [d][c]
                    }
                }
        }
    } else if (MODE == 2) {
        #pragma unroll
        for (int ni = 0; ni < 4; ++ni) {
            const int col = n0 + ni * 16 + cl;
            const int h = col >> 6, dd = col & 63;
            #pragma unroll
            for (int mi = 0; mi < 8; ++mi)
                #pragma unroll
                for (int r = 0; r < 4; ++r) {
                    const int bt = m0 + mi * 16 + rg * 4 + r;
                    const int bb = bt >> 12, t = bt & (T_ - 1);
                    O1[((size_t)(bb * H_ + h) * T_ + t) * 64 + dd] =
                        (short)f2bf(acc[mi][ni][r] * 0.125f);
                }
        }
    } else {
        #pragma unroll
        for (int ni = 0; ni < 4; ++ni) {
            const int col = n0 + ni * 16 + cl;
            #pragma unroll
            for (int mi = 0; mi < 8; ++mi)
                #pragma unroll
                for (int r = 0; r < 4; ++r)
                    Yf[(size_t)(m0 + mi * 16 + rg * 4 + r) * D_ + col] =
                        acc[mi][ni][r];
        }
    }
}

// ---------------------------------------------------------------------------
// K2 (MFMA): per chunk: S = mask(Q K^T); intra = S V^T-op -> OMi bf16;
// ckvT[dd][kd] = sum_c v[c][dd] k[c][kd] -> CKV8 int8 (exact small ints).
// ---------------------------------------------------------------------------
__global__ __launch_bounds__(256)
void k_chunk2(const short* __restrict__ Qb, const short* __restrict__ Kb,
              const short* __restrict__ KbT, const short* __restrict__ VbT,
              short* __restrict__ OMi, signed char* __restrict__ CKV8)
{
    __shared__ __align__(16) short Qs[4096], Ks[4096], KTs[4096], VTs[4096], Ss[4096];
    const int tid = threadIdx.x;
    const int bh = blockIdx.x >> 6, n = blockIdx.x & 63;
    const size_t cbase = ((size_t)bh * T_ + n * 64) * 64;

    auto stage_tile = [&](const short* g, short* l) {
        #pragma unroll
        for (int p = 0; p < 2; ++p) {
            const int off = tid * 16 + p * 4096;
            const int r = off >> 7;
            s16x8 v = *(const s16x8*)(g + (off >> 1));
            *(s16x8*)((char*)l + (off ^ ((r & 7) << 4))) = v;
        }
    };
    stage_tile(Qb  + cbase, Qs);
    stage_tile(Kb  + cbase, Ks);
    stage_tile(KbT + cbase, KTs);
    stage_tile(VbT + cbase, VTs);
    __syncthreads();

    const int lane = tid & 63, w = tid >> 6;
    const int cl = lane & 15, rg = lane >> 4;

    auto frag = [&](const short* l, int rowbase, int kk) -> s16x8 {
        const int row = rowbase + cl;
        int off = row * 128 + kk * 64 + rg * 16;
        off ^= (row & 7) << 4;
        return *(const s16x8*)((const char*)l + off);
    };

    // phase 1: S = Q K^T (masked), bf16 -> Ss
    {
        f32x4 a1[4];
        #pragma unroll
        for (int ni = 0; ni < 4; ++ni) a1[ni] = (f32x4)0.f;
        const s16x8 qa0 = frag(Qs, w * 16, 0), qa1 = frag(Qs, w * 16, 1);
        #pragma unroll
        for (int ni = 0; ni < 4; ++ni) {
            a1[ni] = MFMA16(qa0, frag(Ks, ni * 16, 0), a1[ni]);
            a1[ni] = MFMA16(qa1, frag(Ks, ni * 16, 1), a1[ni]);
        }
        #pragma unroll
        for (int ni = 0; ni < 4; ++ni)
            #pragma unroll
            for (int r = 0; r < 4; ++r) {
                const int i = w * 16 + rg * 4 + r, j = ni * 16 + cl;
                const float v = (j <= i) ? a1[ni][r] : 0.f;
                const int off = (i * 128 + j * 2) ^ ((i & 7) << 4);
                *(short*)((char*)Ss + off) = (short)f2bf(v);
            }
    }
    __syncthreads();

    // phase 2: intra = S * V; phase 3: ckvT[dd][kd]
    f32x4 a2[4], a3[4];
    #pragma unroll
    for (int ni = 0; ni < 4; ++ni) { a2[ni] = (f32x4)0.f; a3[ni] = (f32x4)0.f; }
    {
        const s16x8 sa0 = frag(Ss, w * 16, 0),  sa1 = frag(Ss, w * 16, 1);
        const s16x8 va0 = frag(VTs, w * 16, 0), va1 = frag(VTs, w * 16, 1);
        #pragma unroll
        for (int ni = 0; ni < 4; ++ni) {
            a2[ni] = MFMA16(sa0, frag(VTs, ni * 16, 0), a2[ni]);
            a2[ni] = MFMA16(sa1, frag(VTs, ni * 16, 1), a2[ni]);
            a3[ni] = MFMA16(va0, frag(KTs, ni * 16, 0), a3[ni]);
            a3[ni] = MFMA16(va1, frag(KTs, ni * 16, 1), a3[ni]);
        }
    }
    #pragma unroll
    for (int ni = 0; ni < 4; ++ni)
        #pragma unroll
        for (int r = 0; r < 4; ++r) {
            const int m = w * 16 + rg * 4 + r;     // i for intra, dd for ckv
            const int c = ni * 16 + cl;            // dd for intra, kd for ckv
            const int off = (m * 128 + c * 2) ^ ((m & 7) << 4);
            *(short*)((char*)Qs + off) = (short)f2bf(a2[ni][r]);
            ((signed char*)Ks)[m * 64 + c] = (signed char)(int)a3[ni][r];
        }
    __syncthreads();

    const int bb = bh >> 4, h = bh & 15;
    #pragma unroll
    for (int p = 0; p < 2; ++p) {
        const int off = tid * 16 + p * 4096;
        const int r = off >> 7;
        const int lo = off ^ ((r & 7) << 4);
        s16x8 v = *(const s16x8*)((char*)Qs + lo);
        const size_t gi = ((size_t)bb * T_ + n * 64 + r) * D_
                        + h * 64 + ((off & 127) >> 1);
        *(s16x8*)(OMi + gi) = v;
    }
    {
        const size_t c8 = ((size_t)bh * 64 + n) * 4096;
        *(int4*)(CKV8 + c8 + tid * 16) = *(const int4*)((const char*)Ks + tid * 16);
    }
}

// ---------------------------------------------------------------------------
// K3: integer exclusive scan of CKV8 over chunks -> PB bf16; FM fp32 exact.
// ---------------------------------------------------------------------------
__global__ __launch_bounds__(256)
void k_scan2(const signed char* __restrict__ CKV8, short* __restrict__ PB,
             float* __restrict__ FM, float* __restrict__ FC)
{
    const int bh = blockIdx.x >> 4;
    const int e  = (blockIdx.x & 15) * 256 + threadIdx.x;   // dd*64+kd
    const size_t b8 = (size_t)bh * N_ * 4096 + e;
    const size_t bp = (size_t)bh * N_ * 4096 + e;
    int run = 0;
    #pragma unroll
    for (int nn = 0; nn < 64; ++nn) {
        PB[bp + (size_t)nn * 4096] = (short)f2bf((float)run);
        run += (int)CKV8[b8 + (size_t)nn * 4096];
    }
    FM[(size_t)bh * 4096 + (e & 63) * 64 + (e >> 6)] = (float)run;
    if ((blockIdx.x & 15) == 0 && threadIdx.x == 0) FC[bh] = (float)T_;
}

// ---------------------------------------------------------------------------
// K4 (MFMA): cross = Q @ prefix; OMb = bf16((OMi + cross) / total).
// ---------------------------------------------------------------------------
__global__ __launch_bounds__(256)
void k_cross2(const short* __restrict__ Qb, const short* __restrict__ PB,
              const short* __restrict__ OMi, short* __restrict__ OMb)
{
    __shared__ __align__(16) short Qs[4096], Ps[4096], Cs[4096];
    const int tid = threadIdx.x;
    const int bh = blockIdx.x >> 6, n = blockIdx.x & 63;
    const size_t cbase = ((size_t)bh * T_ + n * 64) * 64;

    auto stage_tile = [&](const short* g, short* l) {
        #pragma unroll
        for (int p = 0; p < 2; ++p) {
            const int off = tid * 16 + p * 4096;
            const int r = off >> 7;
            s16x8 v = *(const s16x8*)(g + (off >> 1));
            *(s16x8*)((char*)l + (off ^ ((r & 7) << 4))) = v;
        }
    };
    stage_tile(Qb + cbase, Qs);
    stage_tile(PB + ((size_t)bh * 64 + n) * 4096, Ps);
    __syncthreads();

    const int lane = tid & 63, w = tid >> 6;
    const int cl = lane & 15, rg = lane >> 4;

    auto frag = [&](const short* l, int rowbase, int kk) -> s16x8 {
        const int row = rowbase + cl;
        int off = row * 128 + kk * 64 + rg * 16;
        off ^= (row & 7) << 4;
        return *(const s16x8*)((const char*)l + off);
    };

    f32x4 a1[4];
    #pragma unroll
    for (int ni = 0; ni < 4; ++ni) a1[ni] = (f32x4)0.f;
    const s16x8 qa0 = frag(Qs, w * 16, 0), qa1 = frag(Qs, w * 16, 1);
    #pragma unroll
    for (int ni = 0; ni < 4; ++ni) {
        a1[ni] = MFMA16(qa0, frag(Ps, ni * 16, 0), a1[ni]);
        a1[ni] = MFMA16(qa1, frag(Ps, ni * 16, 1), a1[ni]);
    }
    #pragma unroll
    for (int ni = 0; ni < 4; ++ni)
        #pragma unroll
        for (int r = 0; r < 4; ++r) {
            const int i = w * 16 + rg * 4 + r, j = ni * 16 + cl;
            const int off = (i * 128 + j * 2) ^ ((i & 7) << 4);
            *(short*)((char*)Cs + off) = (short)f2bf(a1[ni][r]);
        }
    __syncthreads();

    const int bb = bh >> 4, h = bh & 15;
    #pragma unroll
    for (int p = 0; p < 2; ++p) {
        const int off = tid * 16 + p * 4096;
        const int r = off >> 7;
        const int lo = off ^ ((r & 7) << 4);
        s16x8 cv = *(const s16x8*)((char*)Cs + lo);
        const size_t gi = ((size_t)bb * T_ + n * 64 + r) * D_
                        + h * 64 + ((off & 127) >> 1);
        s16x8 iv = *(const s16x8*)(OMi + gi);
        const float invt = 1.0f / (float)(n * 64 + r + 1);
        s16x8 ov;
        #pragma unroll
        for (int j = 0; j < 8; ++j) {
            const float f = (bf2f((unsigned short)iv[j])
                           + bf2f((unsigned short)cv[j])) * invt;
            ov[j] = (short)f2bf(f);
        }
        *(s16x8*)(OMb + gi) = ov;
    }
}

extern "C" void kernel_launch(void* const* d_in, const int* in_sizes, int n_in,
                              void* d_out, int out_size, void* d_ws, size_t ws_size,
                              hipStream_t stream)
{
    const float* X    = (const float*)d_in[0];
    const float* Wqkv = (const float*)d_in[1];
    const float* Wo   = (const float*)d_in[2];

    float* Y  = (float*)d_out;                       // [B,T,D]
    float* FM = Y + (size_t)B_ * T_ * D_;            // [B,H,64,64]
    float* FC = FM + (size_t)B_ * H_ * HD_ * HD_;    // [B,H,1,1]

    char* ws = (char*)d_ws;
    const size_t Mi = 1048576;
    short*       Qb   = (short*)(ws + 0 * Mi);     // 32 MiB
    short*       Kb   = (short*)(ws + 32 * Mi);    // 32 MiB
    short*       KbT  = (short*)(ws + 64 * Mi);    // 32 MiB (early)
    short*       PB   = (short*)(ws + 64 * Mi);    // 32 MiB (late, over KbT)
    short*       VbT  = (short*)(ws + 96 * Mi);    // 32 MiB
    short*       XS   = (short*)(ws + 128 * Mi);   // 64 MiB (early)
    short*       Xb   = (short*)(ws + 128 * Mi);   // 32 MiB (mid, over XS)
    short*       OMi  = (short*)(ws + 128 * Mi);   // 32 MiB (late, over Xb)
    short*       OMb  = (short*)(ws + 160 * Mi);   // 32 MiB
    short*       WSq  = (short*)(ws + 192 * Mi);   //  8 MiB (early)
    signed char* CKV8 = (signed char*)(ws + 192 * Mi); // 16 MiB (late)
    short*       Wqb  = (short*)(ws + 208 * Mi);   //  2 MiB
    short*       WoS  = (short*)(ws + 210 * Mi);   //  2 MiB
    if (ws_size < (size_t)222 * Mi) return;

    dim3 blk(256), blkg(512);
    // X (split) and W_kv (split, rows 1024..3071 of Wqkv)
    k_cvt_split<<<dim3(2048), blk, 0, stream>>>(X, XS, 4194304);
    k_cvt_split<<<dim3(1024), blk, 0, stream>>>(Wqkv + (size_t)1024 * 1024, WSq, 524288);
    // K/V GEMM: split K=2048, N=2048 (256^2 tiles)
    k_gemm<0, 2048, 8><<<dim3(512), blkg, 0, stream>>>(XS, WSq, Kb, KbT, VbT, nullptr);
    // Q GEMM: plain bf16 K=1024 (Xb overwrites XS after kv-GEMM done)
    k_cvt<<<dim3(2048), blk, 0, stream>>>(X, Xb, 4194304);
    k_cvt<<<dim3(512),  blk, 0, stream>>>(Wqkv, Wqb, 262144);
    k_gemm<2, 1024, 4><<<dim3(256), blkg, 0, stream>>>(Xb, Wqb, Qb, nullptr, nullptr, nullptr);
    // chunk-local MFMA work
    k_chunk2<<<dim3(4096), blk, 0, stream>>>(Qb, Kb, KbT, VbT, OMi, CKV8);
    k_scan2 <<<dim3(1024), blk, 0, stream>>>(CKV8, PB, FM, FC);
    k_cross2<<<dim3(4096), blk, 0, stream>>>(Qb, PB, OMi, OMb);
    // output GEMM
    k_cvt<<<dim3(512), blk, 0, stream>>>(Wo, WoS, 262144);
    k_gemm<1, 1024, 4><<<dim3(256), blkg, 0, stream>>>(OMb, WoS, nullptr, nullptr, nullptr, Y);
}